// Round 9
// baseline (1101.133 us; speedup 1.0000x reference)
//
#include <hip/hip_runtime.h>

typedef unsigned short u16;
typedef unsigned int u32;
typedef u16 u16x8 __attribute__((ext_vector_type(8)));
typedef short s16x8 __attribute__((ext_vector_type(8)));
typedef float f32x4 __attribute__((ext_vector_type(4)));

#define NN 32768
#define EE 262144
#define DD 512
#define WMAT (512 * 1024)   // elements per Bt matrix

__device__ __forceinline__ float b2f(u16 u) {
    return __uint_as_float(((u32)u) << 16);
}
__device__ __forceinline__ u16 f2b(float f) {
    u32 u = __float_as_uint(f);
    u32 r = (u + 0x7FFFu + ((u >> 16) & 1u)) >> 16;
    return (u16)r;
}

// -------- edge-index width detection: int64 (high words zero) vs int32 ------------------
__global__ void detect_kernel(const u32* __restrict__ ei, int* __restrict__ flags) {
    if (threadIdx.x == 0) {
        int allzero = 1;
        for (int i = 0; i < 64; ++i)
            if (ei[2 * i + 1] != 0u) allzero = 0;
        flags[0] = allzero;  // 1 => int64 layout
    }
}

__global__ void edges_kernel(const u32* __restrict__ ei, const int* __restrict__ flags,
                             int* __restrict__ s32, int* __restrict__ d32) {
    int t = blockIdx.x * 256 + threadIdx.x;
    u32 s, d;
    if (flags[0]) {  // int64
        s = ei[2 * t];
        d = ei[2 * EE + 2 * t];
    } else {         // int32
        s = ei[t];
        d = ei[EE + t];
    }
    s32[t] = (int)(s & (NN - 1));
    d32[t] = (int)(d & (NN - 1));
}

// -------- weight transpose+cvt: W[e][l][k][n] fp32 -> Bt[e*2+l][n][k 0..1023] bf16 -------
__global__ void transpose_kernel(const float* __restrict__ Wl, const float* __restrict__ Wr,
                                 u16* __restrict__ Bt) {
    int bid = blockIdx.x;
    int matid = bid >> 8;
    int tile = bid & 255;
    int em = matid >> 1;
    int half = matid & 1;
    const float* W = (half ? Wr : Wl) + (size_t)em * DD * DD;
    u16* out = Bt + (size_t)em * DD * 1024 + half * DD;
    int tk = (tile >> 4) * 32, tn = (tile & 15) * 32;
    __shared__ float s[32][33];
    int t = threadIdx.x;
    int rr = t >> 5, cc = t & 31;
#pragma unroll
    for (int p = 0; p < 4; ++p) {
        int kr = p * 8 + rr;
        s[kr][cc] = W[(size_t)(tk + kr) * DD + tn + cc];
    }
    __syncthreads();
#pragma unroll
    for (int p = 0; p < 4; ++p) {
        int nr = p * 8 + rr;
        out[(size_t)(tn + nr) * 1024 + tk + cc] = f2b(s[cc][nr]);
    }
}

// -------- gating (standalone, tiers without xb) ------------------------------------------
__global__ void gate_kernel(const float* __restrict__ x, const float* __restrict__ gw,
                            const float* __restrict__ gb, float* __restrict__ wg) {
    int node = blockIdx.x * 4 + (threadIdx.x >> 6);
    int l = threadIdx.x & 63;
    const f32x4* xr = (const f32x4*)(x + (size_t)node * DD) + l * 2;
    f32x4 x0 = xr[0], x1 = xr[1];
    float a0 = 0.f, a1 = 0.f, a2 = 0.f, a3 = 0.f;
#pragma unroll
    for (int j = 0; j < 8; ++j) {
        float xf = (j < 4) ? x0[j & 3] : x1[j & 3];
        f32x4 wr = ((const f32x4*)gw)[l * 8 + j];
        a0 += xf * wr[0]; a1 += xf * wr[1]; a2 += xf * wr[2]; a3 += xf * wr[3];
    }
#pragma unroll
    for (int off = 32; off > 0; off >>= 1) {
        a0 += __shfl_down(a0, off, 64);
        a1 += __shfl_down(a1, off, 64);
        a2 += __shfl_down(a2, off, 64);
        a3 += __shfl_down(a3, off, 64);
    }
    if (l == 0) {
        float lg[4] = {a0 + gb[0], a1 + gb[1], a2 + gb[2], a3 + gb[3]};
        float m = fmaxf(fmaxf(lg[0], lg[1]), fmaxf(lg[2], lg[3]));
        float p[4]; float s = 0.f;
#pragma unroll
        for (int e = 0; e < 4; ++e) { p[e] = expf(lg[e] - m); s += p[e]; }
        float inv = 1.f / s;
#pragma unroll
        for (int e = 0; e < 4; ++e) p[e] *= inv;
        int i0 = 0;
#pragma unroll
        for (int e = 1; e < 4; ++e) if (p[e] > p[i0]) i0 = e;
        int i1 = -1;
#pragma unroll
        for (int e = 0; e < 4; ++e) if (e != i0 && (i1 < 0 || p[e] > p[i1])) i1 = e;
        float o[4] = {0.f, 0.f, 0.f, 0.f};
        o[i0] = p[i0]; o[i1] = p[i1];
        float* w = wg + (size_t)node * 4;
        w[0] = o[0]; w[1] = o[1]; w[2] = o[2]; w[3] = o[3];
    }
}

// -------- fused gating + fp32->bf16 convert: one pass over x -----------------------------
__global__ void gateconv_kernel(const float* __restrict__ x, const float* __restrict__ gw,
                                const float* __restrict__ gb, float* __restrict__ wg,
                                u16* __restrict__ xb) {
    int node = blockIdx.x * 4 + (threadIdx.x >> 6);
    int l = threadIdx.x & 63;
    const f32x4* xr = (const f32x4*)(x + (size_t)node * DD) + l * 2;
    f32x4 x0 = xr[0], x1 = xr[1];
    u16x8 o8;
    o8[0] = f2b(x0[0]); o8[1] = f2b(x0[1]); o8[2] = f2b(x0[2]); o8[3] = f2b(x0[3]);
    o8[4] = f2b(x1[0]); o8[5] = f2b(x1[1]); o8[6] = f2b(x1[2]); o8[7] = f2b(x1[3]);
    *((u16x8*)(xb + (size_t)node * DD) + l) = o8;
    float a0 = 0.f, a1 = 0.f, a2 = 0.f, a3 = 0.f;
#pragma unroll
    for (int j = 0; j < 8; ++j) {
        float xf = (j < 4) ? x0[j & 3] : x1[j & 3];
        f32x4 wr = ((const f32x4*)gw)[l * 8 + j];
        a0 += xf * wr[0]; a1 += xf * wr[1]; a2 += xf * wr[2]; a3 += xf * wr[3];
    }
#pragma unroll
    for (int off = 32; off > 0; off >>= 1) {
        a0 += __shfl_down(a0, off, 64);
        a1 += __shfl_down(a1, off, 64);
        a2 += __shfl_down(a2, off, 64);
        a3 += __shfl_down(a3, off, 64);
    }
    if (l == 0) {
        float lg[4] = {a0 + gb[0], a1 + gb[1], a2 + gb[2], a3 + gb[3]};
        float m = fmaxf(fmaxf(lg[0], lg[1]), fmaxf(lg[2], lg[3]));
        float p[4]; float s = 0.f;
#pragma unroll
        for (int e = 0; e < 4; ++e) { p[e] = expf(lg[e] - m); s += p[e]; }
        float inv = 1.f / s;
#pragma unroll
        for (int e = 0; e < 4; ++e) p[e] *= inv;
        int i0 = 0;
#pragma unroll
        for (int e = 1; e < 4; ++e) if (p[e] > p[i0]) i0 = e;
        int i1 = -1;
#pragma unroll
        for (int e = 0; e < 4; ++e) if (e != i0 && (i1 < 0 || p[e] > p[i1])) i1 = e;
        float o[4] = {0.f, 0.f, 0.f, 0.f};
        o[i0] = p[i0]; o[i1] = p[i1];
        float* w = wg + (size_t)node * 4;
        w[0] = o[0]; w[1] = o[1]; w[2] = o[2]; w[3] = o[3];
    }
}

// -------- primary/secondary compaction -----------------------------------------------------
// Each node's lower-indexed active expert (e_lo) -> primary list P[e_lo]; the other
// (e_hi) -> secondary list S[e_hi]. Pass-P GEMM plain-stores (covers all nodes, no
// memset); pass-S GEMM does plain += (single writer). Eliminates all atomics in L1.
// lists layout: [0..3]*NN = P lists, [4..7]*NN = S lists (1 MB, aliases dst32).
// posn[node*2+{0,1}] = position in P/S list (512 KB, aliases src32).
__global__ void compact_kernel(const float* __restrict__ wg, int* __restrict__ cnt,
                               int* __restrict__ lists, int* __restrict__ posn) {
    int node = blockIdx.x * 256 + threadIdx.x;
    const float* w = wg + (size_t)node * 4;
    int e0 = -1, e1 = -1;
#pragma unroll
    for (int e = 0; e < 4; ++e)
        if (w[e] > 0.f) { if (e0 < 0) e0 = e; else e1 = e; }
    if (e0 >= 0) {
        int p = atomicAdd(&cnt[e0], 1);
        lists[e0 * NN + p] = node;
        posn[node * 2] = p;
    }
    if (e1 >= 0) {
        int p = atomicAdd(&cnt[4 + e1], 1);
        lists[(4 + e1) * NN + p] = node;
        posn[node * 2 + 1] = p;
    }
}

// cnt layout: [0..3] cntP, [4..7] cntS, [8..11] ebaseP, [12..15] ebaseS, [16] tcP, [17] tcS.
// Compacted aggr1c rows: [0,NN) primaries at ebaseP[e]+pos, [NN,2NN) secondaries.
__global__ void tilemap_kernel(int* __restrict__ cnt, int* __restrict__ tmapP,
                               int* __restrict__ tmapS) {
    if (threadIdx.x == 0) {
        int T = 0, acc = 0;
        for (int e = 0; e < 4; ++e) {
            cnt[8 + e] = acc;
            int c = cnt[e];
            acc += c;
            int nt = (c + 127) >> 7;
            for (int i = 0; i < nt; ++i) tmapP[T++] = (e << 16) | i;
        }
        cnt[16] = T;
        T = 0; acc = 0;
        for (int e = 0; e < 4; ++e) {
            cnt[12 + e] = acc;
            int c = cnt[4 + e];
            acc += c;
            int nt = (c + 127) >> 7;
            for (int i = 0; i < nt; ++i) tmapS[T++] = (e << 16) | i;
        }
        cnt[17] = T;
    }
}

// -------- CSR build ----------------------------------------------------------------------
__global__ void deg_kernel(const int* __restrict__ dst, int* __restrict__ deg) {
    int t = blockIdx.x * blockDim.x + threadIdx.x;
    if (t < EE) atomicAdd(&deg[dst[t]], 1);
}

__global__ void scan1_kernel(const int* __restrict__ deg, int* __restrict__ start,
                             float* __restrict__ invd, int* __restrict__ bsum) {
    int t = threadIdx.x;
    int idx = blockIdx.x * 1024 + t;
    int v = deg[idx];
    int sc = v;
#pragma unroll
    for (int off = 1; off < 64; off <<= 1) {
        int u = __shfl_up(sc, off, 64);
        if ((t & 63) >= off) sc += u;
    }
    __shared__ int wsum[16], woff[16];
    if ((t & 63) == 63) wsum[t >> 6] = sc;
    __syncthreads();
    if (t == 0) {
        int acc = 0;
        for (int w = 0; w < 16; ++w) { woff[w] = acc; acc += wsum[w]; }
        bsum[blockIdx.x] = acc;
    }
    __syncthreads();
    start[idx] = woff[t >> 6] + sc - v;
    invd[idx] = v > 0 ? 1.0f / (float)v : 0.0f;
}

__global__ void scan2_kernel(int* __restrict__ bsum, int* __restrict__ boff) {
    if (threadIdx.x == 0) {
        int acc = 0;
        for (int b = 0; b < 32; ++b) { boff[b] = acc; acc += bsum[b]; }
    }
}

__global__ void scan3_kernel(int* __restrict__ start, int* __restrict__ cursor,
                             const int* __restrict__ boff) {
    int idx = blockIdx.x * 256 + threadIdx.x;
    int s = start[idx] + boff[idx >> 10];
    start[idx] = s;
    cursor[idx] = s;
}

__global__ void scatter_kernel(const int* __restrict__ src, const int* __restrict__ dst,
                               int* __restrict__ cursor, int* __restrict__ csr) {
    int t = blockIdx.x * blockDim.x + threadIdx.x;
    if (t < EE) {
        int d = dst[t];
        int pos = atomicAdd(&cursor[d], 1);
        csr[pos] = src[t];
    }
}

// -------- mean aggregation over CSR; multi-expert: grid = nExp*8192 blocks ---------------
template <bool F32IN>
__global__ void aggr_kernel(const void* __restrict__ hv, u16* __restrict__ outB,
                            const int* __restrict__ start, const int* __restrict__ deg,
                            const int* __restrict__ csr, const float* __restrict__ invd,
                            const float* __restrict__ wg, int eBase, size_t stride) {
    int eo = blockIdx.x >> 13;
    int node = ((blockIdx.x & 8191) << 2) + (threadIdx.x >> 6);
    int expert = eBase + eo;
    if (wg != nullptr && wg[(size_t)node * 4 + expert] == 0.f) return;
    int l = threadIdx.x & 63;
    int s0 = start[node];
    int dg = deg[node];
    u16* out = outB + (size_t)eo * stride;
    const u16* hB = (const u16*)hv + (size_t)eo * stride;
    const float* hF = (const float*)hv + (size_t)eo * stride;
    float a[8] = {0.f, 0.f, 0.f, 0.f, 0.f, 0.f, 0.f, 0.f};

    for (int base = 0; base < dg; base += 64) {
        int cnt = dg - base;
        if (cnt > 64) cnt = 64;
        int vidx = 0;
        if (l < cnt) vidx = csr[s0 + base + l];
        int q = 0;
        if (!F32IN) {
            for (; q + 8 <= cnt; q += 8) {
                int j0 = __shfl(vidx, q, 64);
                int j1 = __shfl(vidx, q + 1, 64);
                int j2 = __shfl(vidx, q + 2, 64);
                int j3 = __shfl(vidx, q + 3, 64);
                int j4 = __shfl(vidx, q + 4, 64);
                int j5 = __shfl(vidx, q + 5, 64);
                int j6 = __shfl(vidx, q + 6, 64);
                int j7 = __shfl(vidx, q + 7, 64);
                u16x8 v0 = *((const u16x8*)(hB + (size_t)j0 * DD) + l);
                u16x8 v1 = *((const u16x8*)(hB + (size_t)j1 * DD) + l);
                u16x8 v2 = *((const u16x8*)(hB + (size_t)j2 * DD) + l);
                u16x8 v3 = *((const u16x8*)(hB + (size_t)j3 * DD) + l);
                u16x8 v4 = *((const u16x8*)(hB + (size_t)j4 * DD) + l);
                u16x8 v5 = *((const u16x8*)(hB + (size_t)j5 * DD) + l);
                u16x8 v6 = *((const u16x8*)(hB + (size_t)j6 * DD) + l);
                u16x8 v7 = *((const u16x8*)(hB + (size_t)j7 * DD) + l);
#pragma unroll
                for (int q2 = 0; q2 < 8; ++q2)
                    a[q2] += ((b2f(v0[q2]) + b2f(v1[q2])) + (b2f(v2[q2]) + b2f(v3[q2]))) +
                             ((b2f(v4[q2]) + b2f(v5[q2])) + (b2f(v6[q2]) + b2f(v7[q2])));
            }
        }
        for (; q + 4 <= cnt; q += 4) {
            int j0 = __shfl(vidx, q, 64);
            int j1 = __shfl(vidx, q + 1, 64);
            int j2 = __shfl(vidx, q + 2, 64);
            int j3 = __shfl(vidx, q + 3, 64);
            if (F32IN) {
                const f32x4* r0 = (const f32x4*)(hF + (size_t)j0 * DD) + l * 2;
                const f32x4* r1 = (const f32x4*)(hF + (size_t)j1 * DD) + l * 2;
                const f32x4* r2 = (const f32x4*)(hF + (size_t)j2 * DD) + l * 2;
                const f32x4* r3 = (const f32x4*)(hF + (size_t)j3 * DD) + l * 2;
                f32x4 u0 = r0[0], u1 = r0[1];
                f32x4 u2 = r1[0], u3 = r1[1];
                f32x4 u4 = r2[0], u5 = r2[1];
                f32x4 u6 = r3[0], u7 = r3[1];
#pragma unroll
                for (int q2 = 0; q2 < 4; ++q2) {
                    a[q2] += (u0[q2] + u2[q2]) + (u4[q2] + u6[q2]);
                    a[4 + q2] += (u1[q2] + u3[q2]) + (u5[q2] + u7[q2]);
                }
            } else {
                u16x8 v0 = *((const u16x8*)(hB + (size_t)j0 * DD) + l);
                u16x8 v1 = *((const u16x8*)(hB + (size_t)j1 * DD) + l);
                u16x8 v2 = *((const u16x8*)(hB + (size_t)j2 * DD) + l);
                u16x8 v3 = *((const u16x8*)(hB + (size_t)j3 * DD) + l);
#pragma unroll
                for (int q2 = 0; q2 < 8; ++q2)
                    a[q2] += (b2f(v0[q2]) + b2f(v1[q2])) + (b2f(v2[q2]) + b2f(v3[q2]));
            }
        }
        for (; q < cnt; ++q) {
            int j = __shfl(vidx, q, 64);
            if (F32IN) {
                const f32x4* r = (const f32x4*)(hF + (size_t)j * DD) + l * 2;
                f32x4 u0 = r[0], u1 = r[1];
#pragma unroll
                for (int q2 = 0; q2 < 4; ++q2) { a[q2] += u0[q2]; a[4 + q2] += u1[q2]; }
            } else {
                u16x8 v = *((const u16x8*)(hB + (size_t)j * DD) + l);
#pragma unroll
                for (int q2 = 0; q2 < 8; ++q2) a[q2] += b2f(v[q2]);
            }
        }
    }
    float sc = invd[node];
    u16x8 o;
#pragma unroll
    for (int q2 = 0; q2 < 8; ++q2) o[q2] = f2b(a[q2] * sc);
    *((u16x8*)(out + (size_t)node * DD) + l) = o;
}

// -------- dual-expert gated aggregation -> COMPACTED P/S output --------------------------
// Primary row at ebaseP[e0]+posP, secondary row at NN+ebaseS[e1]+posS.
__global__ void aggr2_kernel(const u16* __restrict__ h, u16* __restrict__ outC,
                             const int* __restrict__ start, const int* __restrict__ deg,
                             const int* __restrict__ csr, const float* __restrict__ invd,
                             const float* __restrict__ wg, const int* __restrict__ posn,
                             const int* __restrict__ cntb) {
    const int node = (blockIdx.x << 2) + (threadIdx.x >> 6);
    const int l = threadIdx.x & 63;
    const float* w = wg + (size_t)node * 4;
    int e0 = -1, e1 = -1;
#pragma unroll
    for (int e = 0; e < 4; ++e) {
        if (w[e] > 0.f) { if (e0 < 0) e0 = e; else e1 = e; }
    }
    if (e0 < 0) return;
    const int dual = (e1 >= 0);
    if (!dual) e1 = e0;
    const size_t STRE = (size_t)NN * DD;
    const u16* hA = h + (size_t)e0 * STRE;
    const u16* hC = h + (size_t)e1 * STRE;
    const int g0 = cntb[8 + e0] + posn[node * 2];
    const int g1 = NN + cntb[12 + e1] + posn[node * 2 + 1];
    const int s0 = start[node];
    const int dg = deg[node];
    float a0[8] = {0.f, 0.f, 0.f, 0.f, 0.f, 0.f, 0.f, 0.f};
    float a1[8] = {0.f, 0.f, 0.f, 0.f, 0.f, 0.f, 0.f, 0.f};

    for (int base = 0; base < dg; base += 64) {
        int cnt = dg - base;
        if (cnt > 64) cnt = 64;
        int vidx = 0;
        if (l < cnt) vidx = csr[s0 + base + l];
        int q = 0;
        for (; q + 4 <= cnt; q += 4) {
            int j0 = __shfl(vidx, q, 64);
            int j1 = __shfl(vidx, q + 1, 64);
            int j2 = __shfl(vidx, q + 2, 64);
            int j3 = __shfl(vidx, q + 3, 64);
            u16x8 u0 = *((const u16x8*)(hA + (size_t)j0 * DD) + l);
            u16x8 u1 = *((const u16x8*)(hA + (size_t)j1 * DD) + l);
            u16x8 u2 = *((const u16x8*)(hA + (size_t)j2 * DD) + l);
            u16x8 u3 = *((const u16x8*)(hA + (size_t)j3 * DD) + l);
            u16x8 t0 = *((const u16x8*)(hC + (size_t)j0 * DD) + l);
            u16x8 t1 = *((const u16x8*)(hC + (size_t)j1 * DD) + l);
            u16x8 t2 = *((const u16x8*)(hC + (size_t)j2 * DD) + l);
            u16x8 t3 = *((const u16x8*)(hC + (size_t)j3 * DD) + l);
#pragma unroll
            for (int q2 = 0; q2 < 8; ++q2) {
                a0[q2] += (b2f(u0[q2]) + b2f(u1[q2])) + (b2f(u2[q2]) + b2f(u3[q2]));
                a1[q2] += (b2f(t0[q2]) + b2f(t1[q2])) + (b2f(t2[q2]) + b2f(t3[q2]));
            }
        }
        for (; q < cnt; ++q) {
            int j = __shfl(vidx, q, 64);
            u16x8 u = *((const u16x8*)(hA + (size_t)j * DD) + l);
            u16x8 t = *((const u16x8*)(hC + (size_t)j * DD) + l);
#pragma unroll
            for (int q2 = 0; q2 < 8; ++q2) { a0[q2] += b2f(u[q2]); a1[q2] += b2f(t[q2]); }
        }
    }
    float sc = invd[node];
    u16x8 o0, o1;
#pragma unroll
    for (int q2 = 0; q2 < 8; ++q2) { o0[q2] = f2b(a0[q2] * sc); o1[q2] = f2b(a1[q2] * sc); }
    *((u16x8*)(outC + (size_t)g0 * DD) + l) = o0;
    if (dual)
        *((u16x8*)(outC + (size_t)g1 * DD) + l) = o1;
}

__device__ __forceinline__ void gload16(const void* g, void* l) {
    __builtin_amdgcn_global_load_lds((const __attribute__((address_space(1))) void*)g,
                                     (__attribute__((address_space(3))) void*)l, 16, 0, 0);
}

// -------- fused GEMM (L0 + fallback tiers): A and B both staged through LDS --------------
template <bool A2F32>
__global__ void __launch_bounds__(256, 4) gemm_kernel(
    const u16* __restrict__ A1, const u16* __restrict__ A2b, const float* __restrict__ A2f,
    size_t sA, const u16* __restrict__ Bt, size_t sBt,
    const float* __restrict__ bias, size_t sBias,
    u16* __restrict__ Hout, size_t sH, float* __restrict__ Out,
    const float* __restrict__ wg, int mode, int eBase, int ntt) {
    __shared__ u16 lds[A2F32 ? 12288 : 8192];
    u16* ldsA = lds;
    float* ldsF = (float*)lds;
    u16* ldsB = lds + (A2F32 ? 8192 : 4096);
    const int tid = threadIdx.x;
    const int lane = tid & 63;
    const int w = tid >> 6;

    const int bid = blockIdx.x;
    const int xcd = bid & 7;
    const int local = bid >> 3;
    const int mtl = local / ntt;
    const int sub = local - mtl * ntt;
    const int expert = sub >> 2;
    const int wgE = eBase + expert;
    const int m0 = (xcd * 32 + mtl) * 128;
    const int n0 = (sub & 3) * 128;

    const u16* A1p = A1 + (size_t)expert * sA;
    const u16* A2p = A2b + (size_t)expert * sA;
    const u16* Btp = Bt + (size_t)expert * sBt;
    const float* biasp = bias + (size_t)expert * sBias;
    u16* Houtp = Hout + (size_t)expert * sH;

    const int wm = (w >> 1) * 64;
    const int wn = (w & 1) * 64;

    f32x4 acc[4][4];
#pragma unroll
    for (int i = 0; i < 4; ++i)
#pragma unroll
        for (int j = 0; j < 4; ++j) acc[i][j] = (f32x4){0.f, 0.f, 0.f, 0.f};

    const int p0 = tid, p1 = 256 + tid;
    const int r0 = p0 >> 2, c0 = ((p0 & 3) - (r0 >> 1)) & 3;
    const int r1 = p1 >> 2, c1 = ((p1 & 3) - (r1 >> 1)) & 3;
    const int arow = lane & 15;
    const int kc = lane >> 4;

    for (int kb = 0; kb < 32; ++kb) {
        __syncthreads();
        if (!A2F32 || kb < 16) {
            const u16* As = (kb < 16) ? A1p : A2p;
            const int kcol = (kb & 15) * 32;
            gload16(As + (size_t)(m0 + r0) * DD + kcol + c0 * 8, ldsA + p0 * 8);
            gload16(As + (size_t)(m0 + r1) * DD + kcol + c1 * 8, ldsA + p1 * 8);
        } else {
            const float* Af = A2f + (size_t)m0 * DD + (kb - 16) * 32;
#pragma unroll
            for (int q = 0; q < 4; ++q) {
                int p = q * 256 + tid;
                int rr = p >> 3, cpos = p & 7, cc2 = (cpos - rr) & 7;
                gload16(Af + (size_t)rr * DD + cc2 * 4, ldsF + p * 4);
            }
        }
        gload16(Btp + (size_t)(n0 + r0) * 1024 + kb * 32 + c0 * 8, ldsB + p0 * 8);
        gload16(Btp + (size_t)(n0 + r1) * 1024 + kb * 32 + c1 * 8, ldsB + p1 * 8);
        __syncthreads();
        s16x8 af[4], bf[4];
        if (!A2F32 || kb < 16) {
#pragma unroll
            for (int f = 0; f < 4; ++f) {
                int ra = wm + f * 16 + arow;
                int pa = (kc + (ra >> 1)) & 3;
                af[f] = *(const s16x8*)(ldsA + (ra * 4 + pa) * 8);
            }
        } else {
#pragma unroll
            for (int f = 0; f < 4; ++f) {
                int ra = wm + f * 16 + arow;
                int plo = ra * 8 + ((2 * kc + ra) & 7);
                int phi = ra * 8 + ((2 * kc + 1 + ra) & 7);
                f32x4 lo = *(const f32x4*)(ldsF + plo * 4);
                f32x4 hi = *(const f32x4*)(ldsF + phi * 4);
                s16x8 t;
                t[0] = (short)f2b(lo[0]); t[1] = (short)f2b(lo[1]);
                t[2] = (short)f2b(lo[2]); t[3] = (short)f2b(lo[3]);
                t[4] = (short)f2b(hi[0]); t[5] = (short)f2b(hi[1]);
                t[6] = (short)f2b(hi[2]); t[7] = (short)f2b(hi[3]);
                af[f] = t;
            }
        }
#pragma unroll
        for (int f = 0; f < 4; ++f) {
            int rb = wn + f * 16 + arow;
            int pb = (kc + (rb >> 1)) & 3;
            bf[f] = *(const s16x8*)(ldsB + (rb * 4 + pb) * 8);
        }
#pragma unroll
        for (int i = 0; i < 4; ++i)
#pragma unroll
            for (int j = 0; j < 4; ++j)
                acc[i][j] = __builtin_amdgcn_mfma_f32_16x16x32_bf16(af[i], bf[j], acc[i][j], 0, 0, 0);
    }

    const int colq = lane & 15;
    const int rq = lane >> 4;
#pragma unroll
    for (int i = 0; i < 4; ++i) {
#pragma unroll
        for (int j = 0; j < 4; ++j) {
            int col = n0 + wn + j * 16 + colq;
            float bv = biasp[col];
#pragma unroll
            for (int r = 0; r < 4; ++r) {
                int row = m0 + wm + i * 16 + rq * 4 + r;
                float v = fmaxf(acc[i][j][r] + bv, 0.f);
                size_t idx = (size_t)row * DD + col;
                if (mode == 0) {
                    Houtp[idx] = f2b(v);
                } else {
                    float wv = wg[(size_t)row * 4 + wgE];
                    if (mode == 1) {
                        Out[idx] = wv * v;
                    } else if (mode == 2) {
                        if (wv > 0.f) Out[idx] += wv * v;
                    } else {
                        if (wv > 0.f) unsafeAtomicAdd(&Out[idx], wv * v);
                    }
                }
            }
        }
    }
}

// -------- L1 gather-GEMM, P/S two-pass, M=128 x N=64, no atomics -------------------------
// Round-8 post-mortem: atomic epilogue doubled block time (T 97 vs 48.5 us) and 2080
// blocks at 4/CU quantized to ~2.5-3 rounds. Fix: SEC=0 pass plain-stores wv*v for every
// node's primary expert (full coverage -> no memset); SEC=1 pass (stream-ordered after)
// does plain += for the secondary expert (single writer). N=64 shrinks acc to [2][4]
// (32 VGPR; 88 total) -> launch_bounds(256,5) -> 1280-block capacity.
// XCD-local decode kept: 8 n-blocks of tile t all on XCD (t&7).
template <int SEC>
__global__ void __launch_bounds__(256, 5) gemm_gather_kernel(
    const u16* __restrict__ A1c, const u16* __restrict__ A2,
    const u16* __restrict__ Bt, const float* __restrict__ bias,
    float* __restrict__ Out, const float* __restrict__ wg,
    const int* __restrict__ lists, const int* __restrict__ cntb,
    const int* __restrict__ tmap) {
    const int xcd = blockIdx.x & 7;
    const int local = blockIdx.x >> 3;
    const int j8 = local & 7;
    const int slot = local >> 3;
    const int t = slot * 8 + xcd;
    if (t >= cntb[16 + SEC]) return;
    const u32 mi = (u32)tmap[t];
    const int e = mi >> 16;
    const int mt = mi & 0xffff;
    const int cntE = cntb[SEC * 4 + e];
    const int eb = (SEC ? NN : 0) + cntb[8 + SEC * 4 + e];
    const int base = mt << 7;
    const int n0 = j8 * 64;

    __shared__ u16 lds[6144];          // A 128x32 (8 KB) + B 64x32 (4 KB)
    u16* ldsA = lds;
    u16* ldsB = lds + 4096;
    const int tid = threadIdx.x;
    const int lane = tid & 63;
    const int w = tid >> 6;

    const size_t STRE = (size_t)NN * DD;
    const u16* A2p = A2 + (size_t)e * STRE;
    const u16* Btp = Bt + (size_t)e * (2 * WMAT);
    const float* biasp = bias + (size_t)e * 1024;
    const int* listE = lists + (SEC * 4 + e) * NN;

    const int wm = w * 32;             // 4 waves stacked on M; all share full N=64

    f32x4 acc[2][4];
#pragma unroll
    for (int i = 0; i < 2; ++i)
#pragma unroll
        for (int j = 0; j < 4; ++j) acc[i][j] = (f32x4){0.f, 0.f, 0.f, 0.f};

    const int p0 = tid, p1 = 256 + tid;
    const int r0 = p0 >> 2, c0 = ((p0 & 3) - (r0 >> 1)) & 3;
    const int r1 = p1 >> 2, c1 = ((p1 & 3) - (r1 >> 1)) & 3;
    int g0 = eb + base + r0; if (g0 > 2 * NN - 1) g0 = 2 * NN - 1;
    int g1 = eb + base + r1; if (g1 > 2 * NN - 1) g1 = 2 * NN - 1;
    int q0 = base + r0; if (q0 >= cntE) q0 = cntE - 1;
    int q1 = base + r1; if (q1 >= cntE) q1 = cntE - 1;
    const int gr0 = listE[q0];
    const int gr1 = listE[q1];
    const int arow = lane & 15;
    const int kc = lane >> 4;

    for (int kb = 0; kb < 32; ++kb) {
        __syncthreads();
        if (kb < 16) {
            const int kcol = kb * 32;
            gload16(A1c + (size_t)g0 * DD + kcol + c0 * 8, ldsA + p0 * 8);
            gload16(A1c + (size_t)g1 * DD + kcol + c1 * 8, ldsA + p1 * 8);
        } else {
            const int kcol = (kb - 16) * 32;
            gload16(A2p + (size_t)gr0 * DD + kcol + c0 * 8, ldsA + p0 * 8);
            gload16(A2p + (size_t)gr1 * DD + kcol + c1 * 8, ldsA + p1 * 8);
        }
        gload16(Btp + (size_t)(n0 + r0) * 1024 + kb * 32 + c0 * 8, ldsB + p0 * 8);
        __syncthreads();
        s16x8 af[2], bf[4];
#pragma unroll
        for (int f = 0; f < 2; ++f) {
            int ra = wm + f * 16 + arow;
            int pa = (kc + (ra >> 1)) & 3;
            af[f] = *(const s16x8*)(ldsA + (ra * 4 + pa) * 8);
        }
#pragma unroll
        for (int g = 0; g < 4; ++g) {
            int rb = g * 16 + arow;
            int pb = (kc + (rb >> 1)) & 3;
            bf[g] = *(const s16x8*)(ldsB + (rb * 4 + pb) * 8);
        }
#pragma unroll
        for (int i = 0; i < 2; ++i)
#pragma unroll
            for (int j = 0; j < 4; ++j)
                acc[i][j] = __builtin_amdgcn_mfma_f32_16x16x32_bf16(af[i], bf[j], acc[i][j], 0, 0, 0);
    }

    const int colq = lane & 15;
    const int rq = lane >> 4;
#pragma unroll
    for (int f = 0; f < 2; ++f) {
        int nd[4]; float wv4[4]; bool val[4];
#pragma unroll
        for (int r = 0; r < 4; ++r) {
            int rowl = base + wm + f * 16 + rq * 4 + r;
            val[r] = rowl < cntE;
            int qq = val[r] ? rowl : 0;
            nd[r] = listE[qq];
            wv4[r] = wg[(size_t)nd[r] * 4 + e];
        }
#pragma unroll
        for (int g = 0; g < 4; ++g) {
            int col = n0 + g * 16 + colq;
            float bv = biasp[col];
#pragma unroll
            for (int r = 0; r < 4; ++r) {
                if (val[r]) {
                    float v = fmaxf(acc[f][g][r] + bv, 0.f);
                    size_t idx = (size_t)nd[r] * DD + col;
                    if (SEC) Out[idx] += wv4[r] * v;
                    else     Out[idx] = wv4[r] * v;
                }
            }
        }
    }
}

extern "C" void kernel_launch(void* const* d_in, const int* in_sizes, int n_in,
                              void* d_out, int out_size, void* d_ws, size_t ws_size,
                              hipStream_t stream) {
    const float* x  = (const float*)d_in[0];
    const float* gW = (const float*)d_in[1];
    const float* gb = (const float*)d_in[2];
    const float* Wl = (const float*)d_in[3];
    const float* bl = (const float*)d_in[4];
    const float* Wr = (const float*)d_in[5];
    const u32*   ei = (const u32*)d_in[6];
    float* outp = (float*)d_out;

    char* ws = (char*)d_ws;
    size_t off = 0;
    auto alloc = [&](size_t bytes) -> void* {
        void* p = ws + off;
        off += (bytes + 255) & ~(size_t)255;
        return p;
    };
    const size_t MB32 = (size_t)NN * DD * 2;
    const size_t STR = (size_t)NN * DD;      // per-expert element stride
    int*   flags  = (int*)alloc(512);
    float* wg     = (float*)alloc((size_t)NN * 4 * 4);
    int*   deg    = (int*)alloc((size_t)NN * 4);
    int*   start  = (int*)alloc((size_t)NN * 4);
    int*   cursor = (int*)alloc((size_t)NN * 4);
    float* invd   = (float*)alloc((size_t)NN * 4);
    int*   src32  = (int*)alloc((size_t)EE * 4);
    int*   dst32  = (int*)alloc((size_t)EE * 4);
    int*   csr    = (int*)alloc((size_t)EE * 4);
    u16*   Bt     = (u16*)alloc((size_t)8 * WMAT * 2);       // 8 MB
    int*   cnt    = (int*)alloc(128);   // [0..3]cntP [4..7]cntS [8..11]ebP [12..15]ebS [16]tcP [17]tcS
    int*   tmap   = (int*)alloc(1040 * 4);                   // tmapP at 0, tmapS at +520
    // Aliases (dead after scatter_kernel): lists <- dst32 (8*NN ints = 1 MB),
    // posn <- src32 (2*NN ints = 256 KB).
    int*   lists  = dst32;
    int*   posn   = src32;

    size_t rem = (ws_size > off) ? ws_size - off : 0;
    // ws_size ~= 256 MiB on this harness. Tier 0 (compact-fused) = validated 224 MB:
    // xb (32) + h1 (128) + aggr1c (64, compacted 2*NN rows, P then S halves).
    int tier;
    if      (rem >= 7 * MB32 + 65536) tier = 0;   // compact-fused (224 MB)
    else if (rem >= 6 * MB32 + 65536) tier = 2;   // bf16 fused L0, sequential L1 (192 MB)
    else if (rem >= 5 * MB32 + 65536) tier = 3;   // fp32-staged fused L0 (160 MB)
    else if (rem >= 4 * MB32 + 65536) tier = 4;   // sequential (128 MB)
    else                              tier = 5;   // fp32 fallback (96 MB)

    u16 *xb = nullptr, *h1 = nullptr, *aggr1 = nullptr, *aggr0 = nullptr;
    if (tier == 0) {
        xb = (u16*)alloc(MB32);
        h1 = (u16*)alloc(4 * MB32);
        aggr1 = (u16*)alloc(2 * MB32);      // compacted: 2*NN rows
        aggr0 = aggr1;                      // dense L0 aggr (32 MB) aliases head; dead before aggr2
    } else if (tier == 2) {
        xb = (u16*)alloc(MB32);
        h1 = (u16*)alloc(4 * MB32);
        aggr1 = (u16*)alloc(MB32);
        aggr0 = aggr1;
    } else if (tier == 3) {
        aggr0 = (u16*)alloc(MB32);
        h1 = (u16*)alloc(4 * MB32);
        aggr1 = aggr0;
    } else if (tier == 4) {
        aggr0 = (u16*)alloc(MB32);
        xb = (u16*)alloc(MB32);
        h1 = (u16*)alloc(MB32);
        aggr1 = (u16*)alloc(MB32);
    } else {
        aggr0 = (u16*)alloc(MB32);
        h1 = (u16*)alloc(MB32);
        aggr1 = (u16*)alloc(MB32);
    }

    int* bsum = flags + 16;
    int* boff = flags + 64;

    hipMemsetAsync(deg, 0, (size_t)NN * 4, stream);

    detect_kernel<<<1, 64, 0, stream>>>(ei, flags);
    edges_kernel<<<EE / 256, 256, 0, stream>>>(ei, flags, src32, dst32);
    transpose_kernel<<<16 * 256, 256, 0, stream>>>(Wl, Wr, Bt);
    if (xb != nullptr)
        gateconv_kernel<<<NN / 4, 256, 0, stream>>>(x, gW, gb, wg, xb);
    else
        gate_kernel<<<NN / 4, 256, 0, stream>>>(x, gW, gb, wg);
    deg_kernel<<<EE / 256, 256, 0, stream>>>(dst32, deg);
    scan1_kernel<<<32, 1024, 0, stream>>>(deg, start, invd, bsum);
    scan2_kernel<<<1, 64, 0, stream>>>(bsum, boff);
    scan3_kernel<<<NN / 256, 256, 0, stream>>>(start, cursor, boff);
    scatter_kernel<<<EE / 256, 256, 0, stream>>>(src32, dst32, cursor, csr);

    if (tier == 0) {
        // src32/dst32 dead; their storage backs posn/lists from here.
        hipMemsetAsync(cnt, 0, 32, stream);
        compact_kernel<<<NN / 256, 256, 0, stream>>>(wg, cnt, lists, posn);
        tilemap_kernel<<<1, 64, 0, stream>>>(cnt, tmap, tmap + 520);
        // L0: dense aggr + LDS-staged GEMM
        aggr_kernel<false><<<8192, 256, 0, stream>>>(xb, aggr0, start, deg, csr, invd,
                                                     nullptr, 0, 0);
        gemm_kernel<false><<<256 * 16, 256, 0, stream>>>(
            aggr0, xb, nullptr, /*sA=*/0, Bt, /*sBt=*/2 * WMAT, bl, /*sBias=*/1024,
            h1, /*sH=*/STR, nullptr, wg, /*mode=*/0, /*eBase=*/0, /*ntt=*/16);
        // L1: dual-expert aggr -> P/S compacted rows; two plain-store passes (no memset,
        // no atomics). grid = slots(33) x 8 n-blocks x 8 xcds = 2112, covers <= 264 tiles.
        aggr2_kernel<<<8192, 256, 0, stream>>>(h1, aggr1, start, deg, csr, invd, wg,
                                               posn, cnt);
        gemm_gather_kernel<0><<<33 * 8 * 8, 256, 0, stream>>>(
            aggr1, h1, Bt + WMAT, bl + 512, outp, wg, lists, cnt, tmap);
        gemm_gather_kernel<1><<<33 * 8 * 8, 256, 0, stream>>>(
            aggr1, h1, Bt + WMAT, bl + 512, outp, wg, lists, cnt, tmap + 520);
    } else if (tier == 2) {
        aggr_kernel<false><<<8192, 256, 0, stream>>>(xb, aggr0, start, deg, csr, invd,
                                                     nullptr, 0, 0);
        gemm_kernel<false><<<256 * 16, 256, 0, stream>>>(
            aggr0, xb, nullptr, 0, Bt, 2 * WMAT, bl, 1024,
            h1, STR, nullptr, wg, 0, 0, 16);
        for (int e = 0; e < 4; ++e) {
            aggr_kernel<false><<<8192, 256, 0, stream>>>(
                h1 + (size_t)e * STR, aggr1, start, deg, csr, invd, wg, e, 0);
            gemm_kernel<false><<<256 * 4, 256, 0, stream>>>(
                aggr1, h1 + (size_t)e * STR, nullptr, 0,
                Bt + (size_t)(e * 2 + 1) * WMAT, 0, bl + (e * 2 + 1) * 512, 0,
                nullptr, 0, outp, wg, (e == 0) ? 1 : 2, e, 4);
        }
    } else if (tier == 3) {
        aggr_kernel<true><<<8192, 256, 0, stream>>>(x, aggr0, start, deg, csr, invd,
                                                    nullptr, 0, 0);
        gemm_kernel<true><<<256 * 16, 256, 0, stream>>>(
            aggr0, nullptr, x, 0, Bt, 2 * WMAT, bl, 1024,
            h1, STR, nullptr, wg, 0, 0, 16);
        for (int e = 0; e < 4; ++e) {
            aggr_kernel<false><<<8192, 256, 0, stream>>>(
                h1 + (size_t)e * STR, aggr1, start, deg, csr, invd, wg, e, 0);
            gemm_kernel<false><<<256 * 4, 256, 0, stream>>>(
                aggr1, h1 + (size_t)e * STR, nullptr, 0,
                Bt + (size_t)(e * 2 + 1) * WMAT, 0, bl + (e * 2 + 1) * 512, 0,
                nullptr, 0, outp, wg, (e == 0) ? 1 : 2, e, 4);
        }
    } else {
        if (tier == 4) {
            aggr_kernel<false><<<8192, 256, 0, stream>>>(xb, aggr0, start, deg, csr, invd,
                                                         nullptr, 0, 0);
        } else {
            aggr_kernel<true><<<8192, 256, 0, stream>>>(x, aggr0, start, deg, csr, invd,
                                                        nullptr, 0, 0);
        }
        for (int e = 0; e < 4; ++e) {
            const u16* BtL0 = Bt + (size_t)(e * 2 + 0) * WMAT;
            const u16* BtL1 = Bt + (size_t)(e * 2 + 1) * WMAT;
            const float* b0 = bl + (e * 2 + 0) * 512;
            const float* b1 = bl + (e * 2 + 1) * 512;
            if (tier == 4)
                gemm_kernel<false><<<256 * 4, 256, 0, stream>>>(
                    aggr0, xb, nullptr, 0, BtL0, 0, b0, 0, h1, 0, nullptr, wg, 0, e, 4);
            else
                gemm_kernel<true><<<256 * 4, 256, 0, stream>>>(
                    aggr0, nullptr, x, 0, BtL0, 0, b0, 0, h1, 0, nullptr, wg, 0, e, 4);
            aggr_kernel<false><<<8192, 256, 0, stream>>>(h1, aggr1, start, deg, csr, invd,
                                                         wg, e, 0);
            gemm_kernel<false><<<256 * 4, 256, 0, stream>>>(
                aggr1, h1, nullptr, 0, BtL1, 0, b1, 0, nullptr, 0, outp, wg,
                (e == 0) ? 1 : 2, e, 4);
        }
    }
}

// Round 10
// 690.965 us; speedup vs baseline: 1.5936x; 1.5936x over previous
//
#include <hip/hip_runtime.h>

typedef unsigned short u16;
typedef unsigned int u32;
typedef u16 u16x8 __attribute__((ext_vector_type(8)));
typedef short s16x8 __attribute__((ext_vector_type(8)));
typedef float f32x4 __attribute__((ext_vector_type(4)));

#define NN 32768
#define EE 262144
#define DD 512
#define WMAT (512 * 1024)   // elements per Bt matrix

__device__ __forceinline__ float b2f(u16 u) {
    return __uint_as_float(((u32)u) << 16);
}
__device__ __forceinline__ u16 f2b(float f) {
    u32 u = __float_as_uint(f);
    u32 r = (u + 0x7FFFu + ((u >> 16) & 1u)) >> 16;
    return (u16)r;
}

// -------- edge-index width detection: int64 (high words zero) vs int32 ------------------
__global__ void detect_kernel(const u32* __restrict__ ei, int* __restrict__ flags) {
    if (threadIdx.x == 0) {
        int allzero = 1;
        for (int i = 0; i < 64; ++i)
            if (ei[2 * i + 1] != 0u) allzero = 0;
        flags[0] = allzero;  // 1 => int64 layout
    }
}

__global__ void edges_kernel(const u32* __restrict__ ei, const int* __restrict__ flags,
                             int* __restrict__ s32, int* __restrict__ d32) {
    int t = blockIdx.x * 256 + threadIdx.x;
    u32 s, d;
    if (flags[0]) {  // int64
        s = ei[2 * t];
        d = ei[2 * EE + 2 * t];
    } else {         // int32
        s = ei[t];
        d = ei[EE + t];
    }
    s32[t] = (int)(s & (NN - 1));
    d32[t] = (int)(d & (NN - 1));
}

// -------- weight transpose+cvt: W[e][l][k][n] fp32 -> Bt[e*2+l][n][k 0..1023] bf16 -------
__global__ void transpose_kernel(const float* __restrict__ Wl, const float* __restrict__ Wr,
                                 u16* __restrict__ Bt) {
    int bid = blockIdx.x;
    int matid = bid >> 8;
    int tile = bid & 255;
    int em = matid >> 1;
    int half = matid & 1;
    const float* W = (half ? Wr : Wl) + (size_t)em * DD * DD;
    u16* out = Bt + (size_t)em * DD * 1024 + half * DD;
    int tk = (tile >> 4) * 32, tn = (tile & 15) * 32;
    __shared__ float s[32][33];
    int t = threadIdx.x;
    int rr = t >> 5, cc = t & 31;
#pragma unroll
    for (int p = 0; p < 4; ++p) {
        int kr = p * 8 + rr;
        s[kr][cc] = W[(size_t)(tk + kr) * DD + tn + cc];
    }
    __syncthreads();
#pragma unroll
    for (int p = 0; p < 4; ++p) {
        int nr = p * 8 + rr;
        out[(size_t)(tn + nr) * 1024 + tk + cc] = f2b(s[cc][nr]);
    }
}

// -------- gating (standalone, tiers without xb) ------------------------------------------
__global__ void gate_kernel(const float* __restrict__ x, const float* __restrict__ gw,
                            const float* __restrict__ gb, float* __restrict__ wg) {
    int node = blockIdx.x * 4 + (threadIdx.x >> 6);
    int l = threadIdx.x & 63;
    const f32x4* xr = (const f32x4*)(x + (size_t)node * DD) + l * 2;
    f32x4 x0 = xr[0], x1 = xr[1];
    float a0 = 0.f, a1 = 0.f, a2 = 0.f, a3 = 0.f;
#pragma unroll
    for (int j = 0; j < 8; ++j) {
        float xf = (j < 4) ? x0[j & 3] : x1[j & 3];
        f32x4 wr = ((const f32x4*)gw)[l * 8 + j];
        a0 += xf * wr[0]; a1 += xf * wr[1]; a2 += xf * wr[2]; a3 += xf * wr[3];
    }
#pragma unroll
    for (int off = 32; off > 0; off >>= 1) {
        a0 += __shfl_down(a0, off, 64);
        a1 += __shfl_down(a1, off, 64);
        a2 += __shfl_down(a2, off, 64);
        a3 += __shfl_down(a3, off, 64);
    }
    if (l == 0) {
        float lg[4] = {a0 + gb[0], a1 + gb[1], a2 + gb[2], a3 + gb[3]};
        float m = fmaxf(fmaxf(lg[0], lg[1]), fmaxf(lg[2], lg[3]));
        float p[4]; float s = 0.f;
#pragma unroll
        for (int e = 0; e < 4; ++e) { p[e] = expf(lg[e] - m); s += p[e]; }
        float inv = 1.f / s;
#pragma unroll
        for (int e = 0; e < 4; ++e) p[e] *= inv;
        int i0 = 0;
#pragma unroll
        for (int e = 1; e < 4; ++e) if (p[e] > p[i0]) i0 = e;
        int i1 = -1;
#pragma unroll
        for (int e = 0; e < 4; ++e) if (e != i0 && (i1 < 0 || p[e] > p[i1])) i1 = e;
        float o[4] = {0.f, 0.f, 0.f, 0.f};
        o[i0] = p[i0]; o[i1] = p[i1];
        float* w = wg + (size_t)node * 4;
        w[0] = o[0]; w[1] = o[1]; w[2] = o[2]; w[3] = o[3];
    }
}

// -------- fused gating + fp32->bf16 convert: one pass over x -----------------------------
__global__ void gateconv_kernel(const float* __restrict__ x, const float* __restrict__ gw,
                                const float* __restrict__ gb, float* __restrict__ wg,
                                u16* __restrict__ xb) {
    int node = blockIdx.x * 4 + (threadIdx.x >> 6);
    int l = threadIdx.x & 63;
    const f32x4* xr = (const f32x4*)(x + (size_t)node * DD) + l * 2;
    f32x4 x0 = xr[0], x1 = xr[1];
    u16x8 o8;
    o8[0] = f2b(x0[0]); o8[1] = f2b(x0[1]); o8[2] = f2b(x0[2]); o8[3] = f2b(x0[3]);
    o8[4] = f2b(x1[0]); o8[5] = f2b(x1[1]); o8[6] = f2b(x1[2]); o8[7] = f2b(x1[3]);
    *((u16x8*)(xb + (size_t)node * DD) + l) = o8;
    float a0 = 0.f, a1 = 0.f, a2 = 0.f, a3 = 0.f;
#pragma unroll
    for (int j = 0; j < 8; ++j) {
        float xf = (j < 4) ? x0[j & 3] : x1[j & 3];
        f32x4 wr = ((const f32x4*)gw)[l * 8 + j];
        a0 += xf * wr[0]; a1 += xf * wr[1]; a2 += xf * wr[2]; a3 += xf * wr[3];
    }
#pragma unroll
    for (int off = 32; off > 0; off >>= 1) {
        a0 += __shfl_down(a0, off, 64);
        a1 += __shfl_down(a1, off, 64);
        a2 += __shfl_down(a2, off, 64);
        a3 += __shfl_down(a3, off, 64);
    }
    if (l == 0) {
        float lg[4] = {a0 + gb[0], a1 + gb[1], a2 + gb[2], a3 + gb[3]};
        float m = fmaxf(fmaxf(lg[0], lg[1]), fmaxf(lg[2], lg[3]));
        float p[4]; float s = 0.f;
#pragma unroll
        for (int e = 0; e < 4; ++e) { p[e] = expf(lg[e] - m); s += p[e]; }
        float inv = 1.f / s;
#pragma unroll
        for (int e = 0; e < 4; ++e) p[e] *= inv;
        int i0 = 0;
#pragma unroll
        for (int e = 1; e < 4; ++e) if (p[e] > p[i0]) i0 = e;
        int i1 = -1;
#pragma unroll
        for (int e = 0; e < 4; ++e) if (e != i0 && (i1 < 0 || p[e] > p[i1])) i1 = e;
        float o[4] = {0.f, 0.f, 0.f, 0.f};
        o[i0] = p[i0]; o[i1] = p[i1];
        float* w = wg + (size_t)node * 4;
        w[0] = o[0]; w[1] = o[1]; w[2] = o[2]; w[3] = o[3];
    }
}

// -------- primary/secondary compaction -----------------------------------------------------
// Round-9 post-mortem: runtime-indexed atomicAdd(&cnt[e0]) has a DIVERGENT address ->
// compiler cannot wave-coalesce -> 65536 serialized RMWs = 444 us. Fix: unrolled loop
// with LITERAL counter indices (&cnt[e], &cnt[4+e] uniform per iteration) -> compiler
// emits one mbcnt-coalesced atomic per wave per counter (8/wave total), as in rounds 6-8.
// Predicates stay divergent (free); only the address must be uniform.
__global__ void compact_kernel(const float* __restrict__ wg, int* __restrict__ cnt,
                               int* __restrict__ lists, int* __restrict__ posn) {
    int node = blockIdx.x * 256 + threadIdx.x;
    const float* w = wg + (size_t)node * 4;
    float wv[4] = {w[0], w[1], w[2], w[3]};
    int e0 = (wv[0] > 0.f) ? 0 : (wv[1] > 0.f) ? 1 : (wv[2] > 0.f) ? 2 : 3;
#pragma unroll
    for (int e = 0; e < 4; ++e) {
        bool act = wv[e] > 0.f;
        if (act && e == e0) {           // primary (first active expert)
            int p = atomicAdd(&cnt[e], 1);
            lists[e * NN + p] = node;
            posn[node * 2] = p;
        }
        if (act && e != e0) {           // secondary
            int p = atomicAdd(&cnt[4 + e], 1);
            lists[(4 + e) * NN + p] = node;
            posn[node * 2 + 1] = p;
        }
    }
}

// cnt layout: [0..3] cntP, [4..7] cntS, [8..11] ebaseP, [12..15] ebaseS, [16] tcP, [17] tcS.
// Compacted aggr1c rows: [0,NN) primaries at ebaseP[e]+pos, [NN,2NN) secondaries.
__global__ void tilemap_kernel(int* __restrict__ cnt, int* __restrict__ tmapP,
                               int* __restrict__ tmapS) {
    if (threadIdx.x == 0) {
        int T = 0, acc = 0;
        for (int e = 0; e < 4; ++e) {
            cnt[8 + e] = acc;
            int c = cnt[e];
            acc += c;
            int nt = (c + 127) >> 7;
            for (int i = 0; i < nt; ++i) tmapP[T++] = (e << 16) | i;
        }
        cnt[16] = T;
        T = 0; acc = 0;
        for (int e = 0; e < 4; ++e) {
            cnt[12 + e] = acc;
            int c = cnt[4 + e];
            acc += c;
            int nt = (c + 127) >> 7;
            for (int i = 0; i < nt; ++i) tmapS[T++] = (e << 16) | i;
        }
        cnt[17] = T;
    }
}

// -------- CSR build ----------------------------------------------------------------------
__global__ void deg_kernel(const int* __restrict__ dst, int* __restrict__ deg) {
    int t = blockIdx.x * blockDim.x + threadIdx.x;
    if (t < EE) atomicAdd(&deg[dst[t]], 1);
}

__global__ void scan1_kernel(const int* __restrict__ deg, int* __restrict__ start,
                             float* __restrict__ invd, int* __restrict__ bsum) {
    int t = threadIdx.x;
    int idx = blockIdx.x * 1024 + t;
    int v = deg[idx];
    int sc = v;
#pragma unroll
    for (int off = 1; off < 64; off <<= 1) {
        int u = __shfl_up(sc, off, 64);
        if ((t & 63) >= off) sc += u;
    }
    __shared__ int wsum[16], woff[16];
    if ((t & 63) == 63) wsum[t >> 6] = sc;
    __syncthreads();
    if (t == 0) {
        int acc = 0;
        for (int w = 0; w < 16; ++w) { woff[w] = acc; acc += wsum[w]; }
        bsum[blockIdx.x] = acc;
    }
    __syncthreads();
    start[idx] = woff[t >> 6] + sc - v;
    invd[idx] = v > 0 ? 1.0f / (float)v : 0.0f;
}

__global__ void scan2_kernel(int* __restrict__ bsum, int* __restrict__ boff) {
    if (threadIdx.x == 0) {
        int acc = 0;
        for (int b = 0; b < 32; ++b) { boff[b] = acc; acc += bsum[b]; }
    }
}

__global__ void scan3_kernel(int* __restrict__ start, int* __restrict__ cursor,
                             const int* __restrict__ boff) {
    int idx = blockIdx.x * 256 + threadIdx.x;
    int s = start[idx] + boff[idx >> 10];
    start[idx] = s;
    cursor[idx] = s;
}

__global__ void scatter_kernel(const int* __restrict__ src, const int* __restrict__ dst,
                               int* __restrict__ cursor, int* __restrict__ csr) {
    int t = blockIdx.x * blockDim.x + threadIdx.x;
    if (t < EE) {
        int d = dst[t];
        int pos = atomicAdd(&cursor[d], 1);
        csr[pos] = src[t];
    }
}

// -------- mean aggregation over CSR; multi-expert: grid = nExp*8192 blocks ---------------
template <bool F32IN>
__global__ void aggr_kernel(const void* __restrict__ hv, u16* __restrict__ outB,
                            const int* __restrict__ start, const int* __restrict__ deg,
                            const int* __restrict__ csr, const float* __restrict__ invd,
                            const float* __restrict__ wg, int eBase, size_t stride) {
    int eo = blockIdx.x >> 13;
    int node = ((blockIdx.x & 8191) << 2) + (threadIdx.x >> 6);
    int expert = eBase + eo;
    if (wg != nullptr && wg[(size_t)node * 4 + expert] == 0.f) return;
    int l = threadIdx.x & 63;
    int s0 = start[node];
    int dg = deg[node];
    u16* out = outB + (size_t)eo * stride;
    const u16* hB = (const u16*)hv + (size_t)eo * stride;
    const float* hF = (const float*)hv + (size_t)eo * stride;
    float a[8] = {0.f, 0.f, 0.f, 0.f, 0.f, 0.f, 0.f, 0.f};

    for (int base = 0; base < dg; base += 64) {
        int cnt = dg - base;
        if (cnt > 64) cnt = 64;
        int vidx = 0;
        if (l < cnt) vidx = csr[s0 + base + l];
        int q = 0;
        if (!F32IN) {
            for (; q + 8 <= cnt; q += 8) {
                int j0 = __shfl(vidx, q, 64);
                int j1 = __shfl(vidx, q + 1, 64);
                int j2 = __shfl(vidx, q + 2, 64);
                int j3 = __shfl(vidx, q + 3, 64);
                int j4 = __shfl(vidx, q + 4, 64);
                int j5 = __shfl(vidx, q + 5, 64);
                int j6 = __shfl(vidx, q + 6, 64);
                int j7 = __shfl(vidx, q + 7, 64);
                u16x8 v0 = *((const u16x8*)(hB + (size_t)j0 * DD) + l);
                u16x8 v1 = *((const u16x8*)(hB + (size_t)j1 * DD) + l);
                u16x8 v2 = *((const u16x8*)(hB + (size_t)j2 * DD) + l);
                u16x8 v3 = *((const u16x8*)(hB + (size_t)j3 * DD) + l);
                u16x8 v4 = *((const u16x8*)(hB + (size_t)j4 * DD) + l);
                u16x8 v5 = *((const u16x8*)(hB + (size_t)j5 * DD) + l);
                u16x8 v6 = *((const u16x8*)(hB + (size_t)j6 * DD) + l);
                u16x8 v7 = *((const u16x8*)(hB + (size_t)j7 * DD) + l);
#pragma unroll
                for (int q2 = 0; q2 < 8; ++q2)
                    a[q2] += ((b2f(v0[q2]) + b2f(v1[q2])) + (b2f(v2[q2]) + b2f(v3[q2]))) +
                             ((b2f(v4[q2]) + b2f(v5[q2])) + (b2f(v6[q2]) + b2f(v7[q2])));
            }
        }
        for (; q + 4 <= cnt; q += 4) {
            int j0 = __shfl(vidx, q, 64);
            int j1 = __shfl(vidx, q + 1, 64);
            int j2 = __shfl(vidx, q + 2, 64);
            int j3 = __shfl(vidx, q + 3, 64);
            if (F32IN) {
                const f32x4* r0 = (const f32x4*)(hF + (size_t)j0 * DD) + l * 2;
                const f32x4* r1 = (const f32x4*)(hF + (size_t)j1 * DD) + l * 2;
                const f32x4* r2 = (const f32x4*)(hF + (size_t)j2 * DD) + l * 2;
                const f32x4* r3 = (const f32x4*)(hF + (size_t)j3 * DD) + l * 2;
                f32x4 u0 = r0[0], u1 = r0[1];
                f32x4 u2 = r1[0], u3 = r1[1];
                f32x4 u4 = r2[0], u5 = r2[1];
                f32x4 u6 = r3[0], u7 = r3[1];
#pragma unroll
                for (int q2 = 0; q2 < 4; ++q2) {
                    a[q2] += (u0[q2] + u2[q2]) + (u4[q2] + u6[q2]);
                    a[4 + q2] += (u1[q2] + u3[q2]) + (u5[q2] + u7[q2]);
                }
            } else {
                u16x8 v0 = *((const u16x8*)(hB + (size_t)j0 * DD) + l);
                u16x8 v1 = *((const u16x8*)(hB + (size_t)j1 * DD) + l);
                u16x8 v2 = *((const u16x8*)(hB + (size_t)j2 * DD) + l);
                u16x8 v3 = *((const u16x8*)(hB + (size_t)j3 * DD) + l);
#pragma unroll
                for (int q2 = 0; q2 < 8; ++q2)
                    a[q2] += (b2f(v0[q2]) + b2f(v1[q2])) + (b2f(v2[q2]) + b2f(v3[q2]));
            }
        }
        for (; q < cnt; ++q) {
            int j = __shfl(vidx, q, 64);
            if (F32IN) {
                const f32x4* r = (const f32x4*)(hF + (size_t)j * DD) + l * 2;
                f32x4 u0 = r[0], u1 = r[1];
#pragma unroll
                for (int q2 = 0; q2 < 4; ++q2) { a[q2] += u0[q2]; a[4 + q2] += u1[q2]; }
            } else {
                u16x8 v = *((const u16x8*)(hB + (size_t)j * DD) + l);
#pragma unroll
                for (int q2 = 0; q2 < 8; ++q2) a[q2] += b2f(v[q2]);
            }
        }
    }
    float sc = invd[node];
    u16x8 o;
#pragma unroll
    for (int q2 = 0; q2 < 8; ++q2) o[q2] = f2b(a[q2] * sc);
    *((u16x8*)(out + (size_t)node * DD) + l) = o;
}

// -------- dual-expert gated aggregation -> COMPACTED P/S output --------------------------
// Primary row at ebaseP[e0]+posP, secondary row at NN+ebaseS[e1]+posS.
__global__ void aggr2_kernel(const u16* __restrict__ h, u16* __restrict__ outC,
                             const int* __restrict__ start, const int* __restrict__ deg,
                             const int* __restrict__ csr, const float* __restrict__ invd,
                             const float* __restrict__ wg, const int* __restrict__ posn,
                             const int* __restrict__ cntb) {
    const int node = (blockIdx.x << 2) + (threadIdx.x >> 6);
    const int l = threadIdx.x & 63;
    const float* w = wg + (size_t)node * 4;
    int e0 = -1, e1 = -1;
#pragma unroll
    for (int e = 0; e < 4; ++e) {
        if (w[e] > 0.f) { if (e0 < 0) e0 = e; else e1 = e; }
    }
    if (e0 < 0) return;
    const int dual = (e1 >= 0);
    if (!dual) e1 = e0;
    const size_t STRE = (size_t)NN * DD;
    const u16* hA = h + (size_t)e0 * STRE;
    const u16* hC = h + (size_t)e1 * STRE;
    const int g0 = cntb[8 + e0] + posn[node * 2];
    const int g1 = NN + cntb[12 + e1] + posn[node * 2 + 1];
    const int s0 = start[node];
    const int dg = deg[node];
    float a0[8] = {0.f, 0.f, 0.f, 0.f, 0.f, 0.f, 0.f, 0.f};
    float a1[8] = {0.f, 0.f, 0.f, 0.f, 0.f, 0.f, 0.f, 0.f};

    for (int base = 0; base < dg; base += 64) {
        int cnt = dg - base;
        if (cnt > 64) cnt = 64;
        int vidx = 0;
        if (l < cnt) vidx = csr[s0 + base + l];
        int q = 0;
        for (; q + 4 <= cnt; q += 4) {
            int j0 = __shfl(vidx, q, 64);
            int j1 = __shfl(vidx, q + 1, 64);
            int j2 = __shfl(vidx, q + 2, 64);
            int j3 = __shfl(vidx, q + 3, 64);
            u16x8 u0 = *((const u16x8*)(hA + (size_t)j0 * DD) + l);
            u16x8 u1 = *((const u16x8*)(hA + (size_t)j1 * DD) + l);
            u16x8 u2 = *((const u16x8*)(hA + (size_t)j2 * DD) + l);
            u16x8 u3 = *((const u16x8*)(hA + (size_t)j3 * DD) + l);
            u16x8 t0 = *((const u16x8*)(hC + (size_t)j0 * DD) + l);
            u16x8 t1 = *((const u16x8*)(hC + (size_t)j1 * DD) + l);
            u16x8 t2 = *((const u16x8*)(hC + (size_t)j2 * DD) + l);
            u16x8 t3 = *((const u16x8*)(hC + (size_t)j3 * DD) + l);
#pragma unroll
            for (int q2 = 0; q2 < 8; ++q2) {
                a0[q2] += (b2f(u0[q2]) + b2f(u1[q2])) + (b2f(u2[q2]) + b2f(u3[q2]));
                a1[q2] += (b2f(t0[q2]) + b2f(t1[q2])) + (b2f(t2[q2]) + b2f(t3[q2]));
            }
        }
        for (; q < cnt; ++q) {
            int j = __shfl(vidx, q, 64);
            u16x8 u = *((const u16x8*)(hA + (size_t)j * DD) + l);
            u16x8 t = *((const u16x8*)(hC + (size_t)j * DD) + l);
#pragma unroll
            for (int q2 = 0; q2 < 8; ++q2) { a0[q2] += b2f(u[q2]); a1[q2] += b2f(t[q2]); }
        }
    }
    float sc = invd[node];
    u16x8 o0, o1;
#pragma unroll
    for (int q2 = 0; q2 < 8; ++q2) { o0[q2] = f2b(a0[q2] * sc); o1[q2] = f2b(a1[q2] * sc); }
    *((u16x8*)(outC + (size_t)g0 * DD) + l) = o0;
    if (dual)
        *((u16x8*)(outC + (size_t)g1 * DD) + l) = o1;
}

__device__ __forceinline__ void gload16(const void* g, void* l) {
    __builtin_amdgcn_global_load_lds((const __attribute__((address_space(1))) void*)g,
                                     (__attribute__((address_space(3))) void*)l, 16, 0, 0);
}

// -------- fused GEMM (L0 + fallback tiers): A and B both staged through LDS --------------
template <bool A2F32>
__global__ void __launch_bounds__(256, 4) gemm_kernel(
    const u16* __restrict__ A1, const u16* __restrict__ A2b, const float* __restrict__ A2f,
    size_t sA, const u16* __restrict__ Bt, size_t sBt,
    const float* __restrict__ bias, size_t sBias,
    u16* __restrict__ Hout, size_t sH, float* __restrict__ Out,
    const float* __restrict__ wg, int mode, int eBase, int ntt) {
    __shared__ u16 lds[A2F32 ? 12288 : 8192];
    u16* ldsA = lds;
    float* ldsF = (float*)lds;
    u16* ldsB = lds + (A2F32 ? 8192 : 4096);
    const int tid = threadIdx.x;
    const int lane = tid & 63;
    const int w = tid >> 6;

    const int bid = blockIdx.x;
    const int xcd = bid & 7;
    const int local = bid >> 3;
    const int mtl = local / ntt;
    const int sub = local - mtl * ntt;
    const int expert = sub >> 2;
    const int wgE = eBase + expert;
    const int m0 = (xcd * 32 + mtl) * 128;
    const int n0 = (sub & 3) * 128;

    const u16* A1p = A1 + (size_t)expert * sA;
    const u16* A2p = A2b + (size_t)expert * sA;
    const u16* Btp = Bt + (size_t)expert * sBt;
    const float* biasp = bias + (size_t)expert * sBias;
    u16* Houtp = Hout + (size_t)expert * sH;

    const int wm = (w >> 1) * 64;
    const int wn = (w & 1) * 64;

    f32x4 acc[4][4];
#pragma unroll
    for (int i = 0; i < 4; ++i)
#pragma unroll
        for (int j = 0; j < 4; ++j) acc[i][j] = (f32x4){0.f, 0.f, 0.f, 0.f};

    const int p0 = tid, p1 = 256 + tid;
    const int r0 = p0 >> 2, c0 = ((p0 & 3) - (r0 >> 1)) & 3;
    const int r1 = p1 >> 2, c1 = ((p1 & 3) - (r1 >> 1)) & 3;
    const int arow = lane & 15;
    const int kc = lane >> 4;

    for (int kb = 0; kb < 32; ++kb) {
        __syncthreads();
        if (!A2F32 || kb < 16) {
            const u16* As = (kb < 16) ? A1p : A2p;
            const int kcol = (kb & 15) * 32;
            gload16(As + (size_t)(m0 + r0) * DD + kcol + c0 * 8, ldsA + p0 * 8);
            gload16(As + (size_t)(m0 + r1) * DD + kcol + c1 * 8, ldsA + p1 * 8);
        } else {
            const float* Af = A2f + (size_t)m0 * DD + (kb - 16) * 32;
#pragma unroll
            for (int q = 0; q < 4; ++q) {
                int p = q * 256 + tid;
                int rr = p >> 3, cpos = p & 7, cc2 = (cpos - rr) & 7;
                gload16(Af + (size_t)rr * DD + cc2 * 4, ldsF + p * 4);
            }
        }
        gload16(Btp + (size_t)(n0 + r0) * 1024 + kb * 32 + c0 * 8, ldsB + p0 * 8);
        gload16(Btp + (size_t)(n0 + r1) * 1024 + kb * 32 + c1 * 8, ldsB + p1 * 8);
        __syncthreads();
        s16x8 af[4], bf[4];
        if (!A2F32 || kb < 16) {
#pragma unroll
            for (int f = 0; f < 4; ++f) {
                int ra = wm + f * 16 + arow;
                int pa = (kc + (ra >> 1)) & 3;
                af[f] = *(const s16x8*)(ldsA + (ra * 4 + pa) * 8);
            }
        } else {
#pragma unroll
            for (int f = 0; f < 4; ++f) {
                int ra = wm + f * 16 + arow;
                int plo = ra * 8 + ((2 * kc + ra) & 7);
                int phi = ra * 8 + ((2 * kc + 1 + ra) & 7);
                f32x4 lo = *(const f32x4*)(ldsF + plo * 4);
                f32x4 hi = *(const f32x4*)(ldsF + phi * 4);
                s16x8 t;
                t[0] = (short)f2b(lo[0]); t[1] = (short)f2b(lo[1]);
                t[2] = (short)f2b(lo[2]); t[3] = (short)f2b(lo[3]);
                t[4] = (short)f2b(hi[0]); t[5] = (short)f2b(hi[1]);
                t[6] = (short)f2b(hi[2]); t[7] = (short)f2b(hi[3]);
                af[f] = t;
            }
        }
#pragma unroll
        for (int f = 0; f < 4; ++f) {
            int rb = wn + f * 16 + arow;
            int pb = (kc + (rb >> 1)) & 3;
            bf[f] = *(const s16x8*)(ldsB + (rb * 4 + pb) * 8);
        }
#pragma unroll
        for (int i = 0; i < 4; ++i)
#pragma unroll
            for (int j = 0; j < 4; ++j)
                acc[i][j] = __builtin_amdgcn_mfma_f32_16x16x32_bf16(af[i], bf[j], acc[i][j], 0, 0, 0);
    }

    const int colq = lane & 15;
    const int rq = lane >> 4;
#pragma unroll
    for (int i = 0; i < 4; ++i) {
#pragma unroll
        for (int j = 0; j < 4; ++j) {
            int col = n0 + wn + j * 16 + colq;
            float bv = biasp[col];
#pragma unroll
            for (int r = 0; r < 4; ++r) {
                int row = m0 + wm + i * 16 + rq * 4 + r;
                float v = fmaxf(acc[i][j][r] + bv, 0.f);
                size_t idx = (size_t)row * DD + col;
                if (mode == 0) {
                    Houtp[idx] = f2b(v);
                } else {
                    float wv = wg[(size_t)row * 4 + wgE];
                    if (mode == 1) {
                        Out[idx] = wv * v;
                    } else if (mode == 2) {
                        if (wv > 0.f) Out[idx] += wv * v;
                    } else {
                        if (wv > 0.f) unsafeAtomicAdd(&Out[idx], wv * v);
                    }
                }
            }
        }
    }
}

// -------- L1 gather-GEMM, P/S two-pass, M=128 x N=64, no atomics -------------------------
// SEC=0 pass plain-stores wv*v for every node's primary expert (full coverage -> no
// memset); SEC=1 pass (stream-ordered after) does plain += for the secondary expert
// (single writer). N=64: acc [2][4] (32 VGPR) -> launch_bounds(256,5) -> 1280-block cap.
// XCD-local decode: 8 n-blocks of tile t all on XCD (t&7).
template <int SEC>
__global__ void __launch_bounds__(256, 5) gemm_gather_kernel(
    const u16* __restrict__ A1c, const u16* __restrict__ A2,
    const u16* __restrict__ Bt, const float* __restrict__ bias,
    float* __restrict__ Out, const float* __restrict__ wg,
    const int* __restrict__ lists, const int* __restrict__ cntb,
    const int* __restrict__ tmap) {
    const int xcd = blockIdx.x & 7;
    const int local = blockIdx.x >> 3;
    const int j8 = local & 7;
    const int slot = local >> 3;
    const int t = slot * 8 + xcd;
    if (t >= cntb[16 + SEC]) return;
    const u32 mi = (u32)tmap[t];
    const int e = mi >> 16;
    const int mt = mi & 0xffff;
    const int cntE = cntb[SEC * 4 + e];
    const int eb = (SEC ? NN : 0) + cntb[8 + SEC * 4 + e];
    const int base = mt << 7;
    const int n0 = j8 * 64;

    __shared__ u16 lds[6144];          // A 128x32 (8 KB) + B 64x32 (4 KB)
    u16* ldsA = lds;
    u16* ldsB = lds + 4096;
    const int tid = threadIdx.x;
    const int lane = tid & 63;
    const int w = tid >> 6;

    const size_t STRE = (size_t)NN * DD;
    const u16* A2p = A2 + (size_t)e * STRE;
    const u16* Btp = Bt + (size_t)e * (2 * WMAT);
    const float* biasp = bias + (size_t)e * 1024;
    const int* listE = lists + (SEC * 4 + e) * NN;

    const int wm = w * 32;             // 4 waves stacked on M; all share full N=64

    f32x4 acc[2][4];
#pragma unroll
    for (int i = 0; i < 2; ++i)
#pragma unroll
        for (int j = 0; j < 4; ++j) acc[i][j] = (f32x4){0.f, 0.f, 0.f, 0.f};

    const int p0 = tid, p1 = 256 + tid;
    const int r0 = p0 >> 2, c0 = ((p0 & 3) - (r0 >> 1)) & 3;
    const int r1 = p1 >> 2, c1 = ((p1 & 3) - (r1 >> 1)) & 3;
    int g0 = eb + base + r0; if (g0 > 2 * NN - 1) g0 = 2 * NN - 1;
    int g1 = eb + base + r1; if (g1 > 2 * NN - 1) g1 = 2 * NN - 1;
    int q0 = base + r0; if (q0 >= cntE) q0 = cntE - 1;
    int q1 = base + r1; if (q1 >= cntE) q1 = cntE - 1;
    const int gr0 = listE[q0];
    const int gr1 = listE[q1];
    const int arow = lane & 15;
    const int kc = lane >> 4;

    for (int kb = 0; kb < 32; ++kb) {
        __syncthreads();
        if (kb < 16) {
            const int kcol = kb * 32;
            gload16(A1c + (size_t)g0 * DD + kcol + c0 * 8, ldsA + p0 * 8);
            gload16(A1c + (size_t)g1 * DD + kcol + c1 * 8, ldsA + p1 * 8);
        } else {
            const int kcol = (kb - 16) * 32;
            gload16(A2p + (size_t)gr0 * DD + kcol + c0 * 8, ldsA + p0 * 8);
            gload16(A2p + (size_t)gr1 * DD + kcol + c1 * 8, ldsA + p1 * 8);
        }
        gload16(Btp + (size_t)(n0 + r0) * 1024 + kb * 32 + c0 * 8, ldsB + p0 * 8);
        __syncthreads();
        s16x8 af[2], bf[4];
#pragma unroll
        for (int f = 0; f < 2; ++f) {
            int ra = wm + f * 16 + arow;
            int pa = (kc + (ra >> 1)) & 3;
            af[f] = *(const s16x8*)(ldsA + (ra * 4 + pa) * 8);
        }
#pragma unroll
        for (int g = 0; g < 4; ++g) {
            int rb = g * 16 + arow;
            int pb = (kc + (rb >> 1)) & 3;
            bf[g] = *(const s16x8*)(ldsB + (rb * 4 + pb) * 8);
        }
#pragma unroll
        for (int i = 0; i < 2; ++i)
#pragma unroll
            for (int j = 0; j < 4; ++j)
                acc[i][j] = __builtin_amdgcn_mfma_f32_16x16x32_bf16(af[i], bf[j], acc[i][j], 0, 0, 0);
    }

    const int colq = lane & 15;
    const int rq = lane >> 4;
#pragma unroll
    for (int f = 0; f < 2; ++f) {
        int nd[4]; float wv4[4]; bool val[4];
#pragma unroll
        for (int r = 0; r < 4; ++r) {
            int rowl = base + wm + f * 16 + rq * 4 + r;
            val[r] = rowl < cntE;
            int qq = val[r] ? rowl : 0;
            nd[r] = listE[qq];
            wv4[r] = wg[(size_t)nd[r] * 4 + e];
        }
#pragma unroll
        for (int g = 0; g < 4; ++g) {
            int col = n0 + g * 16 + colq;
            float bv = biasp[col];
#pragma unroll
            for (int r = 0; r < 4; ++r) {
                if (val[r]) {
                    float v = fmaxf(acc[f][g][r] + bv, 0.f);
                    size_t idx = (size_t)nd[r] * DD + col;
                    if (SEC) Out[idx] += wv4[r] * v;
                    else     Out[idx] = wv4[r] * v;
                }
            }
        }
    }
}

extern "C" void kernel_launch(void* const* d_in, const int* in_sizes, int n_in,
                              void* d_out, int out_size, void* d_ws, size_t ws_size,
                              hipStream_t stream) {
    const float* x  = (const float*)d_in[0];
    const float* gW = (const float*)d_in[1];
    const float* gb = (const float*)d_in[2];
    const float* Wl = (const float*)d_in[3];
    const float* bl = (const float*)d_in[4];
    const float* Wr = (const float*)d_in[5];
    const u32*   ei = (const u32*)d_in[6];
    float* outp = (float*)d_out;

    char* ws = (char*)d_ws;
    size_t off = 0;
    auto alloc = [&](size_t bytes) -> void* {
        void* p = ws + off;
        off += (bytes + 255) & ~(size_t)255;
        return p;
    };
    const size_t MB32 = (size_t)NN * DD * 2;
    const size_t STR = (size_t)NN * DD;      // per-expert element stride
    int*   flags  = (int*)alloc(512);
    float* wg     = (float*)alloc((size_t)NN * 4 * 4);
    int*   deg    = (int*)alloc((size_t)NN * 4);
    int*   start  = (int*)alloc((size_t)NN * 4);
    int*   cursor = (int*)alloc((size_t)NN * 4);
    float* invd   = (float*)alloc((size_t)NN * 4);
    int*   src32  = (int*)alloc((size_t)EE * 4);
    int*   dst32  = (int*)alloc((size_t)EE * 4);
    int*   csr    = (int*)alloc((size_t)EE * 4);
    u16*   Bt     = (u16*)alloc((size_t)8 * WMAT * 2);       // 8 MB
    int*   cnt    = (int*)alloc(128);   // [0..3]cntP [4..7]cntS [8..11]ebP [12..15]ebS [16]tcP [17]tcS
    int*   tmap   = (int*)alloc(1040 * 4);                   // tmapP at 0, tmapS at +520
    // Aliases (dead after scatter_kernel): lists <- dst32 (8*NN ints = 1 MB),
    // posn <- src32 (2*NN ints = 256 KB).
    int*   lists  = dst32;
    int*   posn   = src32;

    size_t rem = (ws_size > off) ? ws_size - off : 0;
    // ws_size ~= 256 MiB on this harness. Tier 0 (compact-fused) = validated 224 MB:
    // xb (32) + h1 (128) + aggr1c (64, compacted 2*NN rows, P then S halves).
    int tier;
    if      (rem >= 7 * MB32 + 65536) tier = 0;   // compact-fused (224 MB)
    else if (rem >= 6 * MB32 + 65536) tier = 2;   // bf16 fused L0, sequential L1 (192 MB)
    else if (rem >= 5 * MB32 + 65536) tier = 3;   // fp32-staged fused L0 (160 MB)
    else if (rem >= 4 * MB32 + 65536) tier = 4;   // sequential (128 MB)
    else                              tier = 5;   // fp32 fallback (96 MB)

    u16 *xb = nullptr, *h1 = nullptr, *aggr1 = nullptr, *aggr0 = nullptr;
    if (tier == 0) {
        xb = (u16*)alloc(MB32);
        h1 = (u16*)alloc(4 * MB32);
        aggr1 = (u16*)alloc(2 * MB32);      // compacted: 2*NN rows
        aggr0 = aggr1;                      // dense L0 aggr (32 MB) aliases head; dead before aggr2
    } else if (tier == 2) {
        xb = (u16*)alloc(MB32);
        h1 = (u16*)alloc(4 * MB32);
        aggr1 = (u16*)alloc(MB32);
        aggr0 = aggr1;
    } else if (tier == 3) {
        aggr0 = (u16*)alloc(MB32);
        h1 = (u16*)alloc(4 * MB32);
        aggr1 = aggr0;
    } else if (tier == 4) {
        aggr0 = (u16*)alloc(MB32);
        xb = (u16*)alloc(MB32);
        h1 = (u16*)alloc(MB32);
        aggr1 = (u16*)alloc(MB32);
    } else {
        aggr0 = (u16*)alloc(MB32);
        h1 = (u16*)alloc(MB32);
        aggr1 = (u16*)alloc(MB32);
    }

    int* bsum = flags + 16;
    int* boff = flags + 64;

    hipMemsetAsync(deg, 0, (size_t)NN * 4, stream);

    detect_kernel<<<1, 64, 0, stream>>>(ei, flags);
    edges_kernel<<<EE / 256, 256, 0, stream>>>(ei, flags, src32, dst32);
    transpose_kernel<<<16 * 256, 256, 0, stream>>>(Wl, Wr, Bt);
    if (xb != nullptr)
        gateconv_kernel<<<NN / 4, 256, 0, stream>>>(x, gW, gb, wg, xb);
    else
        gate_kernel<<<NN / 4, 256, 0, stream>>>(x, gW, gb, wg);
    deg_kernel<<<EE / 256, 256, 0, stream>>>(dst32, deg);
    scan1_kernel<<<32, 1024, 0, stream>>>(deg, start, invd, bsum);
    scan2_kernel<<<1, 64, 0, stream>>>(bsum, boff);
    scan3_kernel<<<NN / 256, 256, 0, stream>>>(start, cursor, boff);
    scatter_kernel<<<EE / 256, 256, 0, stream>>>(src32, dst32, cursor, csr);

    if (tier == 0) {
        // src32/dst32 dead; their storage backs posn/lists from here.
        hipMemsetAsync(cnt, 0, 32, stream);
        compact_kernel<<<NN / 256, 256, 0, stream>>>(wg, cnt, lists, posn);
        tilemap_kernel<<<1, 64, 0, stream>>>(cnt, tmap, tmap + 520);
        // L0: dense aggr + LDS-staged GEMM
        aggr_kernel<false><<<8192, 256, 0, stream>>>(xb, aggr0, start, deg, csr, invd,
                                                     nullptr, 0, 0);
        gemm_kernel<false><<<256 * 16, 256, 0, stream>>>(
            aggr0, xb, nullptr, /*sA=*/0, Bt, /*sBt=*/2 * WMAT, bl, /*sBias=*/1024,
            h1, /*sH=*/STR, nullptr, wg, /*mode=*/0, /*eBase=*/0, /*ntt=*/16);
        // L1: dual-expert aggr -> P/S compacted rows; two plain-store passes (no memset,
        // no atomics). grid = slots(33) x 8 n-blocks x 8 xcds = 2112, covers <= 264 tiles.
        aggr2_kernel<<<8192, 256, 0, stream>>>(h1, aggr1, start, deg, csr, invd, wg,
                                               posn, cnt);
        gemm_gather_kernel<0><<<33 * 8 * 8, 256, 0, stream>>>(
            aggr1, h1, Bt + WMAT, bl + 512, outp, wg, lists, cnt, tmap);
        gemm_gather_kernel<1><<<33 * 8 * 8, 256, 0, stream>>>(
            aggr1, h1, Bt + WMAT, bl + 512, outp, wg, lists, cnt, tmap + 520);
    } else if (tier == 2) {
        aggr_kernel<false><<<8192, 256, 0, stream>>>(xb, aggr0, start, deg, csr, invd,
                                                     nullptr, 0, 0);
        gemm_kernel<false><<<256 * 16, 256, 0, stream>>>(
            aggr0, xb, nullptr, 0, Bt, 2 * WMAT, bl, 1024,
            h1, STR, nullptr, wg, 0, 0, 16);
        for (int e = 0; e < 4; ++e) {
            aggr_kernel<false><<<8192, 256, 0, stream>>>(
                h1 + (size_t)e * STR, aggr1, start, deg, csr, invd, wg, e, 0);
            gemm_kernel<false><<<256 * 4, 256, 0, stream>>>(
                aggr1, h1 + (size_t)e * STR, nullptr, 0,
                Bt + (size_t)(e * 2 + 1) * WMAT, 0, bl + (e * 2 + 1) * 512, 0,
                nullptr, 0, outp, wg, (e == 0) ? 1 : 2, e, 4);
        }
    } else if (tier == 3) {
        aggr_kernel<true><<<8192, 256, 0, stream>>>(x, aggr0, start, deg, csr, invd,
                                                    nullptr, 0, 0);
        gemm_kernel<true><<<256 * 16, 256, 0, stream>>>(
            aggr0, nullptr, x, 0, Bt, 2 * WMAT, bl, 1024,
            h1, STR, nullptr, wg, 0, 0, 16);
        for (int e = 0; e < 4; ++e) {
            aggr_kernel<false><<<8192, 256, 0, stream>>>(
                h1 + (size_t)e * STR, aggr1, start, deg, csr, invd, wg, e, 0);
            gemm_kernel<false><<<256 * 4, 256, 0, stream>>>(
                aggr1, h1 + (size_t)e * STR, nullptr, 0,
                Bt + (size_t)(e * 2 + 1) * WMAT, 0, bl + (e * 2 + 1) * 512, 0,
                nullptr, 0, outp, wg, (e == 0) ? 1 : 2, e, 4);
        }
    } else {
        if (tier == 4) {
            aggr_kernel<false><<<8192, 256, 0, stream>>>(xb, aggr0, start, deg, csr, invd,
                                                         nullptr, 0, 0);
        } else {
            aggr_kernel<true><<<8192, 256, 0, stream>>>(x, aggr0, start, deg, csr, invd,
                                                        nullptr, 0, 0);
        }
        for (int e = 0; e < 4; ++e) {
            const u16* BtL0 = Bt + (size_t)(e * 2 + 0) * WMAT;
            const u16* BtL1 = Bt + (size_t)(e * 2 + 1) * WMAT;
            const float* b0 = bl + (e * 2 + 0) * 512;
            const float* b1 = bl + (e * 2 + 1) * 512;
            if (tier == 4)
                gemm_kernel<false><<<256 * 4, 256, 0, stream>>>(
                    aggr0, xb, nullptr, 0, BtL0, 0, b0, 0, h1, 0, nullptr, wg, 0, e, 4);
            else
                gemm_kernel<true><<<256 * 4, 256, 0, stream>>>(
                    aggr0, nullptr, x, 0, BtL0, 0, b0, 0, h1, 0, nullptr, wg, 0, e, 4);
            aggr_kernel<false><<<8192, 256, 0, stream>>>(h1, aggr1, start, deg, csr, invd,
                                                         wg, e, 0);
            gemm_kernel<false><<<256 * 4, 256, 0, stream>>>(
                aggr1, h1, nullptr, 0, BtL1, 0, b1, 0, nullptr, 0, outp, wg,
                (e == 0) ? 1 : 2, e, 4);
        }
    }
}

// Round 12
// 656.916 us; speedup vs baseline: 1.6762x; 1.0518x over previous
//
#include <hip/hip_runtime.h>

typedef unsigned short u16;
typedef unsigned int u32;
typedef u16 u16x8 __attribute__((ext_vector_type(8)));
typedef short s16x8 __attribute__((ext_vector_type(8)));
typedef float f32x4 __attribute__((ext_vector_type(4)));

#define NN 32768
#define EE 262144
#define DD 512
#define WMAT (512 * 1024)   // elements per Bt matrix

__device__ __forceinline__ float b2f(u16 u) {
    return __uint_as_float(((u32)u) << 16);
}
__device__ __forceinline__ u16 f2b(float f) {
    u32 u = __float_as_uint(f);
    u32 r = (u + 0x7FFFu + ((u >> 16) & 1u)) >> 16;
    return (u16)r;
}

// -------- edge-index width detection: int64 (high words zero) vs int32 ------------------
__global__ void detect_kernel(const u32* __restrict__ ei, int* __restrict__ flags) {
    if (threadIdx.x == 0) {
        int allzero = 1;
        for (int i = 0; i < 64; ++i)
            if (ei[2 * i + 1] != 0u) allzero = 0;
        flags[0] = allzero;  // 1 => int64 layout
    }
}

__global__ void edges_kernel(const u32* __restrict__ ei, const int* __restrict__ flags,
                             int* __restrict__ s32, int* __restrict__ d32) {
    int t = blockIdx.x * 256 + threadIdx.x;
    u32 s, d;
    if (flags[0]) {  // int64
        s = ei[2 * t];
        d = ei[2 * EE + 2 * t];
    } else {         // int32
        s = ei[t];
        d = ei[EE + t];
    }
    s32[t] = (int)(s & (NN - 1));
    d32[t] = (int)(d & (NN - 1));
}

// -------- weight transpose+cvt: W[e][l][k][n] fp32 -> Bt[e*2+l][n][k 0..1023] bf16 -------
__global__ void transpose_kernel(const float* __restrict__ Wl, const float* __restrict__ Wr,
                                 u16* __restrict__ Bt) {
    int bid = blockIdx.x;
    int matid = bid >> 8;
    int tile = bid & 255;
    int em = matid >> 1;
    int half = matid & 1;
    const float* W = (half ? Wr : Wl) + (size_t)em * DD * DD;
    u16* out = Bt + (size_t)em * DD * 1024 + half * DD;
    int tk = (tile >> 4) * 32, tn = (tile & 15) * 32;
    __shared__ float s[32][33];
    int t = threadIdx.x;
    int rr = t >> 5, cc = t & 31;
#pragma unroll
    for (int p = 0; p < 4; ++p) {
        int kr = p * 8 + rr;
        s[kr][cc] = W[(size_t)(tk + kr) * DD + tn + cc];
    }
    __syncthreads();
#pragma unroll
    for (int p = 0; p < 4; ++p) {
        int nr = p * 8 + rr;
        out[(size_t)(tn + nr) * 1024 + tk + cc] = f2b(s[cc][nr]);
    }
}

// -------- gating (standalone, tiers without xb) ------------------------------------------
__global__ void gate_kernel(const float* __restrict__ x, const float* __restrict__ gw,
                            const float* __restrict__ gb, float* __restrict__ wg) {
    int node = blockIdx.x * 4 + (threadIdx.x >> 6);
    int l = threadIdx.x & 63;
    const f32x4* xr = (const f32x4*)(x + (size_t)node * DD) + l * 2;
    f32x4 x0 = xr[0], x1 = xr[1];
    float a0 = 0.f, a1 = 0.f, a2 = 0.f, a3 = 0.f;
#pragma unroll
    for (int j = 0; j < 8; ++j) {
        float xf = (j < 4) ? x0[j & 3] : x1[j & 3];
        f32x4 wr = ((const f32x4*)gw)[l * 8 + j];
        a0 += xf * wr[0]; a1 += xf * wr[1]; a2 += xf * wr[2]; a3 += xf * wr[3];
    }
#pragma unroll
    for (int off = 32; off > 0; off >>= 1) {
        a0 += __shfl_down(a0, off, 64);
        a1 += __shfl_down(a1, off, 64);
        a2 += __shfl_down(a2, off, 64);
        a3 += __shfl_down(a3, off, 64);
    }
    if (l == 0) {
        float lg[4] = {a0 + gb[0], a1 + gb[1], a2 + gb[2], a3 + gb[3]};
        float m = fmaxf(fmaxf(lg[0], lg[1]), fmaxf(lg[2], lg[3]));
        float p[4]; float s = 0.f;
#pragma unroll
        for (int e = 0; e < 4; ++e) { p[e] = expf(lg[e] - m); s += p[e]; }
        float inv = 1.f / s;
#pragma unroll
        for (int e = 0; e < 4; ++e) p[e] *= inv;
        int i0 = 0;
#pragma unroll
        for (int e = 1; e < 4; ++e) if (p[e] > p[i0]) i0 = e;
        int i1 = -1;
#pragma unroll
        for (int e = 0; e < 4; ++e) if (e != i0 && (i1 < 0 || p[e] > p[i1])) i1 = e;
        float o[4] = {0.f, 0.f, 0.f, 0.f};
        o[i0] = p[i0]; o[i1] = p[i1];
        float* w = wg + (size_t)node * 4;
        w[0] = o[0]; w[1] = o[1]; w[2] = o[2]; w[3] = o[3];
    }
}

// -------- fused gating + fp32->bf16 convert: one pass over x -----------------------------
__global__ void gateconv_kernel(const float* __restrict__ x, const float* __restrict__ gw,
                                const float* __restrict__ gb, float* __restrict__ wg,
                                u16* __restrict__ xb) {
    int node = blockIdx.x * 4 + (threadIdx.x >> 6);
    int l = threadIdx.x & 63;
    const f32x4* xr = (const f32x4*)(x + (size_t)node * DD) + l * 2;
    f32x4 x0 = xr[0], x1 = xr[1];
    u16x8 o8;
    o8[0] = f2b(x0[0]); o8[1] = f2b(x0[1]); o8[2] = f2b(x0[2]); o8[3] = f2b(x0[3]);
    o8[4] = f2b(x1[0]); o8[5] = f2b(x1[1]); o8[6] = f2b(x1[2]); o8[7] = f2b(x1[3]);
    *((u16x8*)(xb + (size_t)node * DD) + l) = o8;
    float a0 = 0.f, a1 = 0.f, a2 = 0.f, a3 = 0.f;
#pragma unroll
    for (int j = 0; j < 8; ++j) {
        float xf = (j < 4) ? x0[j & 3] : x1[j & 3];
        f32x4 wr = ((const f32x4*)gw)[l * 8 + j];
        a0 += xf * wr[0]; a1 += xf * wr[1]; a2 += xf * wr[2]; a3 += xf * wr[3];
    }
#pragma unroll
    for (int off = 32; off > 0; off >>= 1) {
        a0 += __shfl_down(a0, off, 64);
        a1 += __shfl_down(a1, off, 64);
        a2 += __shfl_down(a2, off, 64);
        a3 += __shfl_down(a3, off, 64);
    }
    if (l == 0) {
        float lg[4] = {a0 + gb[0], a1 + gb[1], a2 + gb[2], a3 + gb[3]};
        float m = fmaxf(fmaxf(lg[0], lg[1]), fmaxf(lg[2], lg[3]));
        float p[4]; float s = 0.f;
#pragma unroll
        for (int e = 0; e < 4; ++e) { p[e] = expf(lg[e] - m); s += p[e]; }
        float inv = 1.f / s;
#pragma unroll
        for (int e = 0; e < 4; ++e) p[e] *= inv;
        int i0 = 0;
#pragma unroll
        for (int e = 1; e < 4; ++e) if (p[e] > p[i0]) i0 = e;
        int i1 = -1;
#pragma unroll
        for (int e = 0; e < 4; ++e) if (e != i0 && (i1 < 0 || p[e] > p[i1])) i1 = e;
        float o[4] = {0.f, 0.f, 0.f, 0.f};
        o[i0] = p[i0]; o[i1] = p[i1];
        float* w = wg + (size_t)node * 4;
        w[0] = o[0]; w[1] = o[1]; w[2] = o[2]; w[3] = o[3];
    }
}

// -------- expert-PAIR class compaction ---------------------------------------------------
// Top-2 gating => every node has exactly one unordered expert pair {ea<eb}, one of 6
// classes: (0,1)(0,2)(0,3)(1,2)(1,3)(2,3) -> cls = ea==0 ? eb-1 : ea==1 ? eb+1 : 5.
// One merged gather-GEMM block then computes BOTH experts for 128 same-class nodes and
// writes Out once (plain store, full coverage, no atomics, no second pass).
// Counter atomics stay LITERAL-indexed (round-9/10 lesson: divergent-address atomics
// serialize; literal address + divergent predicate wave-coalesces).
__global__ void compact_kernel(const float* __restrict__ wg, int* __restrict__ cnt,
                               int* __restrict__ list, int* __restrict__ posn) {
    int node = blockIdx.x * 256 + threadIdx.x;
    const float* w = wg + (size_t)node * 4;
    float w0 = w[0], w1 = w[1], w2 = w[2], w3 = w[3];
    int e0 = -1, e1 = -1;
    if (w0 > 0.f) e0 = 0;
    if (w1 > 0.f) { if (e0 < 0) e0 = 1; else if (e1 < 0) e1 = 1; }
    if (w2 > 0.f) { if (e0 < 0) e0 = 2; else if (e1 < 0) e1 = 2; }
    if (w3 > 0.f) { if (e0 < 0) e0 = 3; else if (e1 < 0) e1 = 3; }
    if (e0 < 0) { e0 = 0; e1 = 1; }            // unreachable (softmax>0); 0-weight rows
    if (e1 < 0) e1 = (e0 + 1) & 3;             // single-active fallback (0-weight partner)
    int ea = min(e0, e1), ebx = max(e0, e1);
    int cls = (ea == 0) ? (ebx - 1) : (ea == 1) ? (ebx + 1) : 5;
#pragma unroll
    for (int c = 0; c < 6; ++c) {
        if (cls == c) {
            int p = atomicAdd(&cnt[c], 1);
            list[c * NN + p] = node;
            posn[node] = p;
        }
    }
}

// cnt layout: [0..5] class counts, [8..13] class ebase, [16] tcount.
// Total rows = NN -> 256 full tiles + <=5 padding tails -> tcount <= 262.
__global__ void tilemap_kernel(int* __restrict__ cnt, int* __restrict__ tmap) {
    if (threadIdx.x == 0) {
        int T = 0, acc = 0;
        for (int c = 0; c < 6; ++c) {
            cnt[8 + c] = acc;
            int n = cnt[c];
            acc += n;
            int nt = (n + 127) >> 7;
            for (int i = 0; i < nt; ++i) tmap[T++] = (c << 16) | i;
        }
        cnt[16] = T;
    }
}

// -------- CSR build ----------------------------------------------------------------------
__global__ void deg_kernel(const int* __restrict__ dst, int* __restrict__ deg) {
    int t = blockIdx.x * blockDim.x + threadIdx.x;
    if (t < EE) atomicAdd(&deg[dst[t]], 1);
}

__global__ void scan1_kernel(const int* __restrict__ deg, int* __restrict__ start,
                             float* __restrict__ invd, int* __restrict__ bsum) {
    int t = threadIdx.x;
    int idx = blockIdx.x * 1024 + t;
    int v = deg[idx];
    int sc = v;
#pragma unroll
    for (int off = 1; off < 64; off <<= 1) {
        int u = __shfl_up(sc, off, 64);
        if ((t & 63) >= off) sc += u;
    }
    __shared__ int wsum[16], woff[16];
    if ((t & 63) == 63) wsum[t >> 6] = sc;
    __syncthreads();
    if (t == 0) {
        int acc = 0;
        for (int w = 0; w < 16; ++w) { woff[w] = acc; acc += wsum[w]; }
        bsum[blockIdx.x] = acc;
    }
    __syncthreads();
    start[idx] = woff[t >> 6] + sc - v;
    invd[idx] = v > 0 ? 1.0f / (float)v : 0.0f;
}

__global__ void scan2_kernel(int* __restrict__ bsum, int* __restrict__ boff) {
    if (threadIdx.x == 0) {
        int acc = 0;
        for (int b = 0; b < 32; ++b) { boff[b] = acc; acc += bsum[b]; }
    }
}

__global__ void scan3_kernel(int* __restrict__ start, int* __restrict__ cursor,
                             const int* __restrict__ boff) {
    int idx = blockIdx.x * 256 + threadIdx.x;
    int s = start[idx] + boff[idx >> 10];
    start[idx] = s;
    cursor[idx] = s;
}

__global__ void scatter_kernel(const int* __restrict__ src, const int* __restrict__ dst,
                               int* __restrict__ cursor, int* __restrict__ csr) {
    int t = blockIdx.x * blockDim.x + threadIdx.x;
    if (t < EE) {
        int d = dst[t];
        int pos = atomicAdd(&cursor[d], 1);
        csr[pos] = src[t];
    }
}

// -------- mean aggregation over CSR; multi-expert: grid = nExp*8192 blocks ---------------
template <bool F32IN>
__global__ void aggr_kernel(const void* __restrict__ hv, u16* __restrict__ outB,
                            const int* __restrict__ start, const int* __restrict__ deg,
                            const int* __restrict__ csr, const float* __restrict__ invd,
                            const float* __restrict__ wg, int eBase, size_t stride) {
    int eo = blockIdx.x >> 13;
    int node = ((blockIdx.x & 8191) << 2) + (threadIdx.x >> 6);
    int expert = eBase + eo;
    if (wg != nullptr && wg[(size_t)node * 4 + expert] == 0.f) return;
    int l = threadIdx.x & 63;
    int s0 = start[node];
    int dg = deg[node];
    u16* out = outB + (size_t)eo * stride;
    const u16* hB = (const u16*)hv + (size_t)eo * stride;
    const float* hF = (const float*)hv + (size_t)eo * stride;
    float a[8] = {0.f, 0.f, 0.f, 0.f, 0.f, 0.f, 0.f, 0.f};

    for (int base = 0; base < dg; base += 64) {
        int cnt = dg - base;
        if (cnt > 64) cnt = 64;
        int vidx = 0;
        if (l < cnt) vidx = csr[s0 + base + l];
        int q = 0;
        if (!F32IN) {
            for (; q + 8 <= cnt; q += 8) {
                int j0 = __shfl(vidx, q, 64);
                int j1 = __shfl(vidx, q + 1, 64);
                int j2 = __shfl(vidx, q + 2, 64);
                int j3 = __shfl(vidx, q + 3, 64);
                int j4 = __shfl(vidx, q + 4, 64);
                int j5 = __shfl(vidx, q + 5, 64);
                int j6 = __shfl(vidx, q + 6, 64);
                int j7 = __shfl(vidx, q + 7, 64);
                u16x8 v0 = *((const u16x8*)(hB + (size_t)j0 * DD) + l);
                u16x8 v1 = *((const u16x8*)(hB + (size_t)j1 * DD) + l);
                u16x8 v2 = *((const u16x8*)(hB + (size_t)j2 * DD) + l);
                u16x8 v3 = *((const u16x8*)(hB + (size_t)j3 * DD) + l);
                u16x8 v4 = *((const u16x8*)(hB + (size_t)j4 * DD) + l);
                u16x8 v5 = *((const u16x8*)(hB + (size_t)j5 * DD) + l);
                u16x8 v6 = *((const u16x8*)(hB + (size_t)j6 * DD) + l);
                u16x8 v7 = *((const u16x8*)(hB + (size_t)j7 * DD) + l);
#pragma unroll
                for (int q2 = 0; q2 < 8; ++q2)
                    a[q2] += ((b2f(v0[q2]) + b2f(v1[q2])) + (b2f(v2[q2]) + b2f(v3[q2]))) +
                             ((b2f(v4[q2]) + b2f(v5[q2])) + (b2f(v6[q2]) + b2f(v7[q2])));
            }
        }
        for (; q + 4 <= cnt; q += 4) {
            int j0 = __shfl(vidx, q, 64);
            int j1 = __shfl(vidx, q + 1, 64);
            int j2 = __shfl(vidx, q + 2, 64);
            int j3 = __shfl(vidx, q + 3, 64);
            if (F32IN) {
                const f32x4* r0 = (const f32x4*)(hF + (size_t)j0 * DD) + l * 2;
                const f32x4* r1 = (const f32x4*)(hF + (size_t)j1 * DD) + l * 2;
                const f32x4* r2 = (const f32x4*)(hF + (size_t)j2 * DD) + l * 2;
                const f32x4* r3 = (const f32x4*)(hF + (size_t)j3 * DD) + l * 2;
                f32x4 u0 = r0[0], u1 = r0[1];
                f32x4 u2 = r1[0], u3 = r1[1];
                f32x4 u4 = r2[0], u5 = r2[1];
                f32x4 u6 = r3[0], u7 = r3[1];
#pragma unroll
                for (int q2 = 0; q2 < 4; ++q2) {
                    a[q2] += (u0[q2] + u2[q2]) + (u4[q2] + u6[q2]);
                    a[4 + q2] += (u1[q2] + u3[q2]) + (u5[q2] + u7[q2]);
                }
            } else {
                u16x8 v0 = *((const u16x8*)(hB + (size_t)j0 * DD) + l);
                u16x8 v1 = *((const u16x8*)(hB + (size_t)j1 * DD) + l);
                u16x8 v2 = *((const u16x8*)(hB + (size_t)j2 * DD) + l);
                u16x8 v3 = *((const u16x8*)(hB + (size_t)j3 * DD) + l);
#pragma unroll
                for (int q2 = 0; q2 < 8; ++q2)
                    a[q2] += (b2f(v0[q2]) + b2f(v1[q2])) + (b2f(v2[q2]) + b2f(v3[q2]));
            }
        }
        for (; q < cnt; ++q) {
            int j = __shfl(vidx, q, 64);
            if (F32IN) {
                const f32x4* r = (const f32x4*)(hF + (size_t)j * DD) + l * 2;
                f32x4 u0 = r[0], u1 = r[1];
#pragma unroll
                for (int q2 = 0; q2 < 4; ++q2) { a[q2] += u0[q2]; a[4 + q2] += u1[q2]; }
            } else {
                u16x8 v = *((const u16x8*)(hB + (size_t)j * DD) + l);
#pragma unroll
                for (int q2 = 0; q2 < 8; ++q2) a[q2] += b2f(v[q2]);
            }
        }
    }
    float sc = invd[node];
    u16x8 o;
#pragma unroll
    for (int q2 = 0; q2 < 8; ++q2) o[q2] = f2b(a[q2] * sc);
    *((u16x8*)(out + (size_t)node * DD) + l) = o;
}

// -------- dual-expert gated aggregation -> class-compacted output ------------------------
// Node's lower-expert aggregation -> row g = ebase[cls]+posn[node]; higher -> row NN+g.
// Both rows always written (e0/e1 fallback IDENTICAL to compact_kernel's).
__global__ void aggr2_kernel(const u16* __restrict__ h, u16* __restrict__ outC,
                             const int* __restrict__ start, const int* __restrict__ deg,
                             const int* __restrict__ csr, const float* __restrict__ invd,
                             const float* __restrict__ wg, const int* __restrict__ posn,
                             const int* __restrict__ cntb) {
    const int node = (blockIdx.x << 2) + (threadIdx.x >> 6);
    const int l = threadIdx.x & 63;
    const float* w = wg + (size_t)node * 4;
    float w0 = w[0], w1 = w[1], w2 = w[2], w3 = w[3];
    int e0 = -1, e1 = -1;
    if (w0 > 0.f) e0 = 0;
    if (w1 > 0.f) { if (e0 < 0) e0 = 1; else if (e1 < 0) e1 = 1; }
    if (w2 > 0.f) { if (e0 < 0) e0 = 2; else if (e1 < 0) e1 = 2; }
    if (w3 > 0.f) { if (e0 < 0) e0 = 3; else if (e1 < 0) e1 = 3; }
    if (e0 < 0) { e0 = 0; e1 = 1; }
    if (e1 < 0) e1 = (e0 + 1) & 3;
    const int ea = min(e0, e1), ebx = max(e0, e1);
    const int cls = (ea == 0) ? (ebx - 1) : (ea == 1) ? (ebx + 1) : 5;
    const int g = cntb[8 + cls] + posn[node];
    const size_t STRE = (size_t)NN * DD;
    const u16* hA = h + (size_t)ea * STRE;
    const u16* hC = h + (size_t)ebx * STRE;
    const int s0 = start[node];
    const int dg = deg[node];
    float a0[8] = {0.f, 0.f, 0.f, 0.f, 0.f, 0.f, 0.f, 0.f};
    float a1[8] = {0.f, 0.f, 0.f, 0.f, 0.f, 0.f, 0.f, 0.f};

    for (int base = 0; base < dg; base += 64) {
        int cnt = dg - base;
        if (cnt > 64) cnt = 64;
        int vidx = 0;
        if (l < cnt) vidx = csr[s0 + base + l];
        int q = 0;
        for (; q + 4 <= cnt; q += 4) {
            int j0 = __shfl(vidx, q, 64);
            int j1 = __shfl(vidx, q + 1, 64);
            int j2 = __shfl(vidx, q + 2, 64);
            int j3 = __shfl(vidx, q + 3, 64);
            u16x8 u0 = *((const u16x8*)(hA + (size_t)j0 * DD) + l);
            u16x8 u1 = *((const u16x8*)(hA + (size_t)j1 * DD) + l);
            u16x8 u2 = *((const u16x8*)(hA + (size_t)j2 * DD) + l);
            u16x8 u3 = *((const u16x8*)(hA + (size_t)j3 * DD) + l);
            u16x8 t0 = *((const u16x8*)(hC + (size_t)j0 * DD) + l);
            u16x8 t1 = *((const u16x8*)(hC + (size_t)j1 * DD) + l);
            u16x8 t2 = *((const u16x8*)(hC + (size_t)j2 * DD) + l);
            u16x8 t3 = *((const u16x8*)(hC + (size_t)j3 * DD) + l);
#pragma unroll
            for (int q2 = 0; q2 < 8; ++q2) {
                a0[q2] += (b2f(u0[q2]) + b2f(u1[q2])) + (b2f(u2[q2]) + b2f(u3[q2]));
                a1[q2] += (b2f(t0[q2]) + b2f(t1[q2])) + (b2f(t2[q2]) + b2f(t3[q2]));
            }
        }
        for (; q < cnt; ++q) {
            int j = __shfl(vidx, q, 64);
            u16x8 u = *((const u16x8*)(hA + (size_t)j * DD) + l);
            u16x8 t = *((const u16x8*)(hC + (size_t)j * DD) + l);
#pragma unroll
            for (int q2 = 0; q2 < 8; ++q2) { a0[q2] += b2f(u[q2]); a1[q2] += b2f(t[q2]); }
        }
    }
    float sc = invd[node];
    u16x8 o0, o1;
#pragma unroll
    for (int q2 = 0; q2 < 8; ++q2) { o0[q2] = f2b(a0[q2] * sc); o1[q2] = f2b(a1[q2] * sc); }
    *((u16x8*)(outC + (size_t)g * DD) + l) = o0;
    *((u16x8*)(outC + (size_t)(NN + g) * DD) + l) = o1;
}

__device__ __forceinline__ void gload16(const void* g, void* l) {
    __builtin_amdgcn_global_load_lds((const __attribute__((address_space(1))) void*)g,
                                     (__attribute__((address_space(3))) void*)l, 16, 0, 0);
}

// -------- fused GEMM (L0 + fallback tiers): A and B both staged through LDS --------------
template <bool A2F32>
__global__ void __launch_bounds__(256, 4) gemm_kernel(
    const u16* __restrict__ A1, const u16* __restrict__ A2b, const float* __restrict__ A2f,
    size_t sA, const u16* __restrict__ Bt, size_t sBt,
    const float* __restrict__ bias, size_t sBias,
    u16* __restrict__ Hout, size_t sH, float* __restrict__ Out,
    const float* __restrict__ wg, int mode, int eBase, int ntt) {
    __shared__ u16 lds[A2F32 ? 12288 : 8192];
    u16* ldsA = lds;
    float* ldsF = (float*)lds;
    u16* ldsB = lds + (A2F32 ? 8192 : 4096);
    const int tid = threadIdx.x;
    const int lane = tid & 63;
    const int w = tid >> 6;

    const int bid = blockIdx.x;
    const int xcd = bid & 7;
    const int local = bid >> 3;
    const int mtl = local / ntt;
    const int sub = local - mtl * ntt;
    const int expert = sub >> 2;
    const int wgE = eBase + expert;
    const int m0 = (xcd * 32 + mtl) * 128;
    const int n0 = (sub & 3) * 128;

    const u16* A1p = A1 + (size_t)expert * sA;
    const u16* A2p = A2b + (size_t)expert * sA;
    const u16* Btp = Bt + (size_t)expert * sBt;
    const float* biasp = bias + (size_t)expert * sBias;
    u16* Houtp = Hout + (size_t)expert * sH;

    const int wm = (w >> 1) * 64;
    const int wn = (w & 1) * 64;

    f32x4 acc[4][4];
#pragma unroll
    for (int i = 0; i < 4; ++i)
#pragma unroll
        for (int j = 0; j < 4; ++j) acc[i][j] = (f32x4){0.f, 0.f, 0.f, 0.f};

    const int p0 = tid, p1 = 256 + tid;
    const int r0 = p0 >> 2, c0 = ((p0 & 3) - (r0 >> 1)) & 3;
    const int r1 = p1 >> 2, c1 = ((p1 & 3) - (r1 >> 1)) & 3;
    const int arow = lane & 15;
    const int kc = lane >> 4;

    for (int kb = 0; kb < 32; ++kb) {
        __syncthreads();
        if (!A2F32 || kb < 16) {
            const u16* As = (kb < 16) ? A1p : A2p;
            const int kcol = (kb & 15) * 32;
            gload16(As + (size_t)(m0 + r0) * DD + kcol + c0 * 8, ldsA + p0 * 8);
            gload16(As + (size_t)(m0 + r1) * DD + kcol + c1 * 8, ldsA + p1 * 8);
        } else {
            const float* Af = A2f + (size_t)m0 * DD + (kb - 16) * 32;
#pragma unroll
            for (int q = 0; q < 4; ++q) {
                int p = q * 256 + tid;
                int rr = p >> 3, cpos = p & 7, cc2 = (cpos - rr) & 7;
                gload16(Af + (size_t)rr * DD + cc2 * 4, ldsF + p * 4);
            }
        }
        gload16(Btp + (size_t)(n0 + r0) * 1024 + kb * 32 + c0 * 8, ldsB + p0 * 8);
        gload16(Btp + (size_t)(n0 + r1) * 1024 + kb * 32 + c1 * 8, ldsB + p1 * 8);
        __syncthreads();
        s16x8 af[4], bf[4];
        if (!A2F32 || kb < 16) {
#pragma unroll
            for (int f = 0; f < 4; ++f) {
                int ra = wm + f * 16 + arow;
                int pa = (kc + (ra >> 1)) & 3;
                af[f] = *(const s16x8*)(ldsA + (ra * 4 + pa) * 8);
            }
        } else {
#pragma unroll
            for (int f = 0; f < 4; ++f) {
                int ra = wm + f * 16 + arow;
                int plo = ra * 8 + ((2 * kc + ra) & 7);
                int phi = ra * 8 + ((2 * kc + 1 + ra) & 7);
                f32x4 lo = *(const f32x4*)(ldsF + plo * 4);
                f32x4 hi = *(const f32x4*)(ldsF + phi * 4);
                s16x8 t;
                t[0] = (short)f2b(lo[0]); t[1] = (short)f2b(lo[1]);
                t[2] = (short)f2b(lo[2]); t[3] = (short)f2b(lo[3]);
                t[4] = (short)f2b(hi[0]); t[5] = (short)f2b(hi[1]);
                t[6] = (short)f2b(hi[2]); t[7] = (short)f2b(hi[3]);
                af[f] = t;
            }
        }
#pragma unroll
        for (int f = 0; f < 4; ++f) {
            int rb = wn + f * 16 + arow;
            int pb = (kc + (rb >> 1)) & 3;
            bf[f] = *(const s16x8*)(ldsB + (rb * 4 + pb) * 8);
        }
#pragma unroll
        for (int i = 0; i < 4; ++i)
#pragma unroll
            for (int j = 0; j < 4; ++j)
                acc[i][j] = __builtin_amdgcn_mfma_f32_16x16x32_bf16(af[i], bf[j], acc[i][j], 0, 0, 0);
    }

    const int colq = lane & 15;
    const int rq = lane >> 4;
#pragma unroll
    for (int i = 0; i < 4; ++i) {
#pragma unroll
        for (int j = 0; j < 4; ++j) {
            int col = n0 + wn + j * 16 + colq;
            float bv = biasp[col];
#pragma unroll
            for (int r = 0; r < 4; ++r) {
                int row = m0 + wm + i * 16 + rq * 4 + r;
                float v = fmaxf(acc[i][j][r] + bv, 0.f);
                size_t idx = (size_t)row * DD + col;
                if (mode == 0) {
                    Houtp[idx] = f2b(v);
                } else {
                    float wv = wg[(size_t)row * 4 + wgE];
                    if (mode == 1) {
                        Out[idx] = wv * v;
                    } else if (mode == 2) {
                        if (wv > 0.f) Out[idx] += wv * v;
                    } else {
                        if (wv > 0.f) unsafeAtomicAdd(&Out[idx], wv * v);
                    }
                }
            }
        }
    }
}

// -------- merged L1 gather-GEMM: one block = 128 same-class nodes x BOTH experts ---------
// out[node] = w_lo*relu([aggr_lo|h_lo]@Bt_lo^T + b_lo) + w_hi*relu(... hi ...), one plain
// fp32 store, full coverage (every node in exactly one class) -> no memset, no atomics,
// no pass serialization. 16 MFMA per barrier-pair (dense-kernel density; the P/S split
// had 8). A panels for both experts are class-linear (aggr2 writes them compacted);
// h1 gathers via class list. XCD-local: 8 n-blocks of tile t all on XCD (t&7).
__global__ void __launch_bounds__(256, 4) gemm_gather_kernel(
    const u16* __restrict__ A1c, const u16* __restrict__ A2,
    const u16* __restrict__ Bt, const float* __restrict__ bias,
    float* __restrict__ Out, const float* __restrict__ wg,
    const int* __restrict__ lists, const int* __restrict__ cntb,
    const int* __restrict__ tmap) {
    const int xcd = blockIdx.x & 7;
    const int local = blockIdx.x >> 3;
    const int j8 = local & 7;
    const int slot = local >> 3;
    const int t = slot * 8 + xcd;
    if (t >= cntb[16]) return;
    const u32 mi = (u32)tmap[t];
    const int cls = mi >> 16;
    const int mt = mi & 0xffff;
    const int cntC = cntb[cls];
    const int ebase = cntb[8 + cls];
    const int base = mt << 7;
    const int n0 = j8 * 64;
    const int ea = (cls < 3) ? 0 : ((cls < 5) ? 1 : 2);
    const int eh = (cls < 3) ? (cls + 1) : ((cls < 5) ? (cls - 1) : 3);

    __shared__ u16 lds[12288];         // Alo 8K | Ahi 8K | Blo 4K | Bhi 4K (bytes)
    u16* ldsAlo = lds;
    u16* ldsAhi = lds + 4096;
    u16* ldsBlo = lds + 8192;
    u16* ldsBhi = lds + 10240;
    const int tid = threadIdx.x;
    const int lane = tid & 63;
    const int w = tid >> 6;

    const size_t STRE = (size_t)NN * DD;
    const u16* hLo = A2 + (size_t)ea * STRE;
    const u16* hHi = A2 + (size_t)eh * STRE;
    const u16* BtLo = Bt + (size_t)ea * (2 * WMAT);
    const u16* BtHi = Bt + (size_t)eh * (2 * WMAT);
    const float* bLo = bias + (size_t)ea * 1024;
    const float* bHi = bias + (size_t)eh * 1024;
    const int* listC = lists + cls * NN;

    const int wm = w * 32;             // 4 waves stacked on M; all share full N=64

    f32x4 accL[2][4], accH[2][4];
#pragma unroll
    for (int i = 0; i < 2; ++i)
#pragma unroll
        for (int j = 0; j < 4; ++j) {
            accL[i][j] = (f32x4){0.f, 0.f, 0.f, 0.f};
            accH[i][j] = (f32x4){0.f, 0.f, 0.f, 0.f};
        }

    const int p0 = tid, p1 = 256 + tid;
    const int r0 = p0 >> 2, c0 = ((p0 & 3) - (r0 >> 1)) & 3;
    const int r1 = p1 >> 2, c1 = ((p1 & 3) - (r1 >> 1)) & 3;
    int g0 = ebase + base + r0; if (g0 > NN - 1) g0 = NN - 1;   // pad rows: any valid row
    int g1 = ebase + base + r1; if (g1 > NN - 1) g1 = NN - 1;
    int q0 = base + r0; if (q0 >= cntC) q0 = cntC - 1;          // cntC>=1 (tile exists)
    int q1 = base + r1; if (q1 >= cntC) q1 = cntC - 1;
    const int gr0 = listC[q0];
    const int gr1 = listC[q1];
    const int arow = lane & 15;
    const int kc = lane >> 4;

    for (int kb = 0; kb < 32; ++kb) {
        __syncthreads();
        if (kb < 16) {
            const int kcol = kb * 32;
            gload16(A1c + (size_t)g0 * DD + kcol + c0 * 8, ldsAlo + p0 * 8);
            gload16(A1c + (size_t)g1 * DD + kcol + c1 * 8, ldsAlo + p1 * 8);
            gload16(A1c + (size_t)(NN + g0) * DD + kcol + c0 * 8, ldsAhi + p0 * 8);
            gload16(A1c + (size_t)(NN + g1) * DD + kcol + c1 * 8, ldsAhi + p1 * 8);
        } else {
            const int kcol = (kb - 16) * 32;
            gload16(hLo + (size_t)gr0 * DD + kcol + c0 * 8, ldsAlo + p0 * 8);
            gload16(hLo + (size_t)gr1 * DD + kcol + c1 * 8, ldsAlo + p1 * 8);
            gload16(hHi + (size_t)gr0 * DD + kcol + c0 * 8, ldsAhi + p0 * 8);
            gload16(hHi + (size_t)gr1 * DD + kcol + c1 * 8, ldsAhi + p1 * 8);
        }
        gload16(BtLo + (size_t)(n0 + r0) * 1024 + kb * 32 + c0 * 8, ldsBlo + p0 * 8);
        gload16(BtHi + (size_t)(n0 + r0) * 1024 + kb * 32 + c0 * 8, ldsBhi + p0 * 8);
        __syncthreads();
        // lo expert (frags read then consumed before hi frags -> peak VGPR stays low)
        {
            s16x8 af[2], bf[4];
#pragma unroll
            for (int f = 0; f < 2; ++f) {
                int ra = wm + f * 16 + arow;
                int pa = (kc + (ra >> 1)) & 3;
                af[f] = *(const s16x8*)(ldsAlo + (ra * 4 + pa) * 8);
            }
#pragma unroll
            for (int g2 = 0; g2 < 4; ++g2) {
                int rb = g2 * 16 + arow;
                int pb = (kc + (rb >> 1)) & 3;
                bf[g2] = *(const s16x8*)(ldsBlo + (rb * 4 + pb) * 8);
            }
#pragma unroll
            for (int i = 0; i < 2; ++i)
#pragma unroll
                for (int j = 0; j < 4; ++j)
                    accL[i][j] = __builtin_amdgcn_mfma_f32_16x16x32_bf16(af[i], bf[j], accL[i][j], 0, 0, 0);
        }
        // hi expert
        {
            s16x8 af[2], bf[4];
#pragma unroll
            for (int f = 0; f < 2; ++f) {
                int ra = wm + f * 16 + arow;
                int pa = (kc + (ra >> 1)) & 3;
                af[f] = *(const s16x8*)(ldsAhi + (ra * 4 + pa) * 8);
            }
#pragma unroll
            for (int g2 = 0; g2 < 4; ++g2) {
                int rb = g2 * 16 + arow;
                int pb = (kc + (rb >> 1)) & 3;
                bf[g2] = *(const s16x8*)(ldsBhi + (rb * 4 + pb) * 8);
            }
#pragma unroll
            for (int i = 0; i < 2; ++i)
#pragma unroll
                for (int j = 0; j < 4; ++j)
                    accH[i][j] = __builtin_amdgcn_mfma_f32_16x16x32_bf16(af[i], bf[j], accH[i][j], 0, 0, 0);
        }
    }

    const int colq = lane & 15;
    const int rq = lane >> 4;
#pragma unroll
    for (int f = 0; f < 2; ++f) {
        int nd[4]; float wlo[4], whi[4]; bool val[4];
#pragma unroll
        for (int r = 0; r < 4; ++r) {
            int rowl = base + wm + f * 16 + rq * 4 + r;
            val[r] = rowl < cntC;
            int qq = val[r] ? rowl : 0;
            nd[r] = listC[qq];
            wlo[r] = wg[(size_t)nd[r] * 4 + ea];
            whi[r] = wg[(size_t)nd[r] * 4 + eh];
        }
#pragma unroll
        for (int g2 = 0; g2 < 4; ++g2) {
            int col = n0 + g2 * 16 + colq;
            float bvL = bLo[col];
            float bvH = bHi[col];
#pragma unroll
            for (int r = 0; r < 4; ++r) {
                if (val[r]) {
                    float vL = fmaxf(accL[f][g2][r] + bvL, 0.f);
                    float vH = fmaxf(accH[f][g2][r] + bvH, 0.f);
                    Out[(size_t)nd[r] * DD + col] = wlo[r] * vL + whi[r] * vH;
                }
            }
        }
    }
}

extern "C" void kernel_launch(void* const* d_in, const int* in_sizes, int n_in,
                              void* d_out, int out_size, void* d_ws, size_t ws_size,
                              hipStream_t stream) {
    const float* x  = (const float*)d_in[0];
    const float* gW = (const float*)d_in[1];
    const float* gb = (const float*)d_in[2];
    const float* Wl = (const float*)d_in[3];
    const float* bl = (const float*)d_in[4];
    const float* Wr = (const float*)d_in[5];
    const u32*   ei = (const u32*)d_in[6];
    float* outp = (float*)d_out;

    char* ws = (char*)d_ws;
    size_t off = 0;
    auto alloc = [&](size_t bytes) -> void* {
        void* p = ws + off;
        off += (bytes + 255) & ~(size_t)255;
        return p;
    };
    const size_t MB32 = (size_t)NN * DD * 2;
    const size_t STR = (size_t)NN * DD;      // per-expert element stride
    int*   flags  = (int*)alloc(512);
    float* wg     = (float*)alloc((size_t)NN * 4 * 4);
    int*   deg    = (int*)alloc((size_t)NN * 4);
    int*   start  = (int*)alloc((size_t)NN * 4);
    int*   cursor = (int*)alloc((size_t)NN * 4);
    float* invd   = (float*)alloc((size_t)NN * 4);
    int*   src32  = (int*)alloc((size_t)EE * 4);
    int*   dst32  = (int*)alloc((size_t)EE * 4);
    int*   csr    = (int*)alloc((size_t)EE * 4);
    u16*   Bt     = (u16*)alloc((size_t)8 * WMAT * 2);       // 8 MB
    int*   cnt    = (int*)alloc(128);   // [0..5] cls counts, [8..13] ebase, [16] tcount
    int*   tmap   = (int*)alloc(1040 * 4);
    // Aliases (dead after scatter_kernel): lists <- dst32 (6*NN ints = 768 KB of 1 MB),
    // posn <- src32 (NN ints).
    int*   lists  = dst32;
    int*   posn   = src32;

    size_t rem = (ws_size > off) ? ws_size - off : 0;
    // ws_size ~= 256 MiB on this harness. Tier 0 (compact-fused) = validated 224 MB:
    // xb (32) + h1 (128) + aggr1c (64, class-compacted lo/hi halves of NN rows each).
    int tier;
    if      (rem >= 7 * MB32 + 65536) tier = 0;   // compact-fused (224 MB)
    else if (rem >= 6 * MB32 + 65536) tier = 2;   // bf16 fused L0, sequential L1 (192 MB)
    else if (rem >= 5 * MB32 + 65536) tier = 3;   // fp32-staged fused L0 (160 MB)
    else if (rem >= 4 * MB32 + 65536) tier = 4;   // sequential (128 MB)
    else                              tier = 5;   // fp32 fallback (96 MB)

    u16 *xb = nullptr, *h1 = nullptr, *aggr1 = nullptr, *aggr0 = nullptr;
    if (tier == 0) {
        xb = (u16*)alloc(MB32);
        h1 = (u16*)alloc(4 * MB32);
        aggr1 = (u16*)alloc(2 * MB32);      // compacted: 2*NN rows (lo half, hi half)
        aggr0 = aggr1;                      // dense L0 aggr aliases head; dead before aggr2
    } else if (tier == 2) {
        xb = (u16*)alloc(MB32);
        h1 = (u16*)alloc(4 * MB32);
        aggr1 = (u16*)alloc(MB32);
        aggr0 = aggr1;
    } else if (tier == 3) {
        aggr0 = (u16*)alloc(MB32);
        h1 = (u16*)alloc(4 * MB32);
        aggr1 = aggr0;
    } else if (tier == 4) {
        aggr0 = (u16*)alloc(MB32);
        xb = (u16*)alloc(MB32);
        h1 = (u16*)alloc(MB32);
        aggr1 = (u16*)alloc(MB32);
    } else {
        aggr0 = (u16*)alloc(MB32);
        h1 = (u16*)alloc(MB32);
        aggr1 = (u16*)alloc(MB32);
    }

    int* bsum = flags + 16;
    int* boff = flags + 64;

    hipMemsetAsync(deg, 0, (size_t)NN * 4, stream);

    detect_kernel<<<1, 64, 0, stream>>>(ei, flags);
    edges_kernel<<<EE / 256, 256, 0, stream>>>(ei, flags, src32, dst32);
    transpose_kernel<<<16 * 256, 256, 0, stream>>>(Wl, Wr, Bt);
    if (xb != nullptr)
        gateconv_kernel<<<NN / 4, 256, 0, stream>>>(x, gW, gb, wg, xb);
    else
        gate_kernel<<<NN / 4, 256, 0, stream>>>(x, gW, gb, wg);
    deg_kernel<<<EE / 256, 256, 0, stream>>>(dst32, deg);
    scan1_kernel<<<32, 1024, 0, stream>>>(deg, start, invd, bsum);
    scan2_kernel<<<1, 64, 0, stream>>>(bsum, boff);
    scan3_kernel<<<NN / 256, 256, 0, stream>>>(start, cursor, boff);
    scatter_kernel<<<EE / 256, 256, 0, stream>>>(src32, dst32, cursor, csr);

    if (tier == 0) {
        // src32/dst32 dead; their storage backs posn/lists from here.
        hipMemsetAsync(cnt, 0, 32, stream);
        compact_kernel<<<NN / 256, 256, 0, stream>>>(wg, cnt, lists, posn);
        tilemap_kernel<<<1, 64, 0, stream>>>(cnt, tmap);
        // L0: dense aggr + LDS-staged GEMM
        aggr_kernel<false><<<8192, 256, 0, stream>>>(xb, aggr0, start, deg, csr, invd,
                                                     nullptr, 0, 0);
        gemm_kernel<false><<<256 * 16, 256, 0, stream>>>(
            aggr0, xb, nullptr, /*sA=*/0, Bt, /*sBt=*/2 * WMAT, bl, /*sBias=*/1024,
            h1, /*sH=*/STR, nullptr, wg, /*mode=*/0, /*eBase=*/0, /*ntt=*/16);
        // L1: dual-expert aggr -> class-compacted rows; ONE merged both-expert gather
        // GEMM, plain stores, full coverage. grid = slots(33) x 8 n-blocks x 8 xcds.
        aggr2_kernel<<<8192, 256, 0, stream>>>(h1, aggr1, start, deg, csr, invd, wg,
                                               posn, cnt);
        gemm_gather_kernel<<<33 * 8 * 8, 256, 0, stream>>>(
            aggr1, h1, Bt + WMAT, bl + 512, outp, wg, lists, cnt, tmap);
    } else if (tier == 2) {
        aggr_kernel<false><<<8192, 256, 0, stream>>>(xb, aggr0, start, deg, csr, invd,
                                                     nullptr, 0, 0);
        gemm_kernel<false><<<256 * 16, 256, 0, stream>>>(
            aggr0, xb, nullptr, 0, Bt, 2 * WMAT, bl, 1024,
            h1, STR, nullptr, wg, 0, 0, 16);
        for (int e = 0; e < 4; ++e) {
            aggr_kernel<false><<<8192, 256, 0, stream>>>(
                h1 + (size_t)e * STR, aggr1, start, deg, csr, invd, wg, e, 0);
            gemm_kernel<false><<<256 * 4, 256, 0, stream>>>(
                aggr1, h1 + (size_t)e * STR, nullptr, 0,
                Bt + (size_t)(e * 2 + 1) * WMAT, 0, bl + (e * 2 + 1) * 512, 0,
                nullptr, 0, outp, wg, (e == 0) ? 1 : 2, e, 4);
        }
    } else if (tier == 3) {
        aggr_kernel<true><<<8192, 256, 0, stream>>>(x, aggr0, start, deg, csr, invd,
                                                    nullptr, 0, 0);
        gemm_kernel<true><<<256 * 16, 256, 0, stream>>>(
            aggr0, nullptr, x, 0, Bt, 2 * WMAT, bl, 1024,
            h1, STR, nullptr, wg, 0, 0, 16);
        for (int e = 0; e < 4; ++e) {
            aggr_kernel<false><<<8192, 256, 0, stream>>>(
                h1 + (size_t)e * STR, aggr1, start, deg, csr, invd, wg, e, 0);
            gemm_kernel<false><<<256 * 4, 256, 0, stream>>>(
                aggr1, h1 + (size_t)e * STR, nullptr, 0,
                Bt + (size_t)(e * 2 + 1) * WMAT, 0, bl + (e * 2 + 1) * 512, 0,
                nullptr, 0, outp, wg, (e == 0) ? 1 : 2, e, 4);
        }
    } else {
        if (tier == 4) {
            aggr_kernel<false><<<8192, 256, 0, stream>>>(xb, aggr0, start, deg, csr, invd,
                                                         nullptr, 0, 0);
        } else {
            aggr_kernel<true><<<8192, 256, 0, stream>>>(x, aggr0, start, deg, csr, invd,
                                                        nullptr, 0, 0);
        }
        for (int e = 0; e < 4; ++e) {
            const u16* BtL0 = Bt + (size_t)(e * 2 + 0) * WMAT;
            const u16* BtL1 = Bt + (size_t)(e * 2 + 1) * WMAT;
            const float* b0 = bl + (e * 2 + 0) * 512;
            const float* b1 = bl + (e * 2 + 1) * 512;
            if (tier == 4)
                gemm_kernel<false><<<256 * 4, 256, 0, stream>>>(
                    aggr0, xb, nullptr, 0, BtL0, 0, b0, 0, h1, 0, nullptr, wg, 0, e, 4);
            else
                gemm_kernel<true><<<256 * 4, 256, 0, stream>>>(
                    aggr0, nullptr, x, 0, BtL0, 0, b0, 0, h1, 0, nullptr, wg, 0, e, 4);
            aggr_kernel<false><<<8192, 256, 0, stream>>>(h1, aggr1, start, deg, csr, invd,
                                                         wg, e, 0);
            gemm_kernel<false><<<256 * 4, 256, 0, stream>>>(
                aggr1, h1, nullptr, 0, BtL1, 0, b1, 0, nullptr, 0, outp, wg,
                (e == 0) ? 1 : 2, e, 4);
        }
    }
}